// Round 7
// baseline (671.633 us; speedup 1.0000x reference)
//
#include <hip/hip_runtime.h>
#include <math.h>

#define NN 50000
#define EE 800000
#define NB 196     // ceil(NN/256) : scan blocks AND coarse buckets (256 nodes each)
#define CAP 6144   // bucket capacity (mean 4081, sigma~64 -> 32 sigma margin)

typedef __attribute__((ext_vector_type(8))) short bf16x8;
typedef __attribute__((ext_vector_type(16))) float f32x16;
typedef __attribute__((ext_vector_type(4))) unsigned short us4;

__device__ inline unsigned short bf16_rne(float f) {
    union { float f; unsigned u; } a; a.f = f;
    unsigned u = a.u;
    u += 0x7fff + ((u >> 16) & 1);
    return (unsigned short)(u >> 16);
}
__device__ inline float bf16_to_f32(unsigned short u) {
    union { unsigned u; float f; } a; a.u = ((unsigned)u) << 16;
    return a.f;
}

// ---------------- CSR build: bucketed counting sort ----------------
// pass 1: append record ((dst&255)<<16 | src) to coarse bucket dst>>8
__global__ void bin_kernel(const int* __restrict__ src, const int* __restrict__ dst,
                           int* __restrict__ bcur, int* __restrict__ rec, int E) {
    int e = blockIdx.x * 256 + threadIdx.x;
    if (e >= E) return;
    int s = src[e], d = dst[e];
    int cb = d >> 8;
    int p = atomicAdd(&bcur[cb], 1);
    if (p < CAP) rec[(size_t)cb * CAP + p] = ((d & 255) << 16) | s;
}

// pass 2a: per-bucket LDS histogram -> deg (no global atomics, coalesced write)
__global__ __launch_bounds__(256) void bucket_deg_kernel(
        const int* __restrict__ rec, const int* __restrict__ bcur,
        int* __restrict__ deg, int n) {
    __shared__ int cnt[256];
    const int cb = blockIdx.x, t = threadIdx.x;
    cnt[t] = 0;
    __syncthreads();
    int m = bcur[cb]; if (m > CAP) m = CAP;
    const int* r = rec + (size_t)cb * CAP;
    for (int i = t; i < m; i += 256) atomicAdd(&cnt[r[i] >> 16], 1);
    __syncthreads();
    int node = cb * 256 + t;
    if (node < n) deg[node] = cnt[t];
}

// scan phase 1: per-block sums of deg
__global__ void scan1_kernel(const int* __restrict__ deg, int* __restrict__ bsum, int n) {
    __shared__ int s[256];
    int t = threadIdx.x;
    int i = blockIdx.x * 256 + t;
    s[t] = (i < n) ? deg[i] : 0;
    __syncthreads();
    for (int ofs = 128; ofs > 0; ofs >>= 1) {
        if (t < ofs) s[t] += s[t + ofs];
        __syncthreads();
    }
    if (t == 0) bsum[blockIdx.x] = s[0];
}

// scan phase 2: exclusive scan of block sums
__global__ void scan2_kernel(int* __restrict__ bsum, int nb) {
    __shared__ int s[256];
    int t = threadIdx.x;
    s[t] = (t < nb) ? bsum[t] : 0;
    __syncthreads();
    for (int ofs = 1; ofs < 256; ofs <<= 1) {
        int v = s[t];
        int a = (t >= ofs) ? s[t - ofs] : 0;
        __syncthreads();
        s[t] = v + a;
        __syncthreads();
    }
    if (t < nb) bsum[t] = (t == 0) ? 0 : s[t - 1];
}

// scan phase 3: in-block exclusive scan + block offset -> rowoff
__global__ void scan3_kernel(const int* __restrict__ deg, const int* __restrict__ bsum,
                             int* __restrict__ rowoff, int n) {
    __shared__ int s[256];
    int t = threadIdx.x;
    int i = blockIdx.x * 256 + t;
    int d = (i < n) ? deg[i] : 0;
    s[t] = d;
    __syncthreads();
    for (int ofs = 1; ofs < 256; ofs <<= 1) {
        int v = s[t];
        int a = (t >= ofs) ? s[t - ofs] : 0;
        __syncthreads();
        s[t] = v + a;
        __syncthreads();
    }
    int excl = s[t] - d + bsum[blockIdx.x];
    if (i < n) rowoff[i] = excl;
    if (i == n - 1) rowoff[n] = excl + d;
}

// pass 2b: per-bucket LDS counting sort -> contiguous coalesced csr segment write
__global__ __launch_bounds__(256) void place_kernel(
        const int* __restrict__ rec, const int* __restrict__ bcur,
        const int* __restrict__ rowoff, unsigned short* __restrict__ csr, int n) {
    __shared__ int cnt[256];
    __shared__ int cur[256];
    __shared__ unsigned short sorted[CAP];
    const int cb = blockIdx.x, t = threadIdx.x;
    int m = bcur[cb]; if (m > CAP) m = CAP;
    const int* r = rec + (size_t)cb * CAP;

    cnt[t] = 0;
    __syncthreads();
    for (int i = t; i < m; i += 256) atomicAdd(&cnt[r[i] >> 16], 1);
    __syncthreads();
    int orig = cnt[t];
    // inclusive scan of cnt
    for (int ofs = 1; ofs < 256; ofs <<= 1) {
        int v = cnt[t];
        int a = (t >= ofs) ? cnt[t - ofs] : 0;
        __syncthreads();
        cnt[t] = v + a;
        __syncthreads();
    }
    cur[t] = cnt[t] - orig;   // exclusive offset (doubles as scatter cursor)
    __syncthreads();
    for (int i = t; i < m; i += 256) {
        int rr = r[i];
        int pos = atomicAdd(&cur[rr >> 16], 1);
        sorted[pos] = (unsigned short)(rr & 0xffff);
    }
    __syncthreads();
    const int base = rowoff[cb * 256];   // bucket's csr segment start (cb*256 < n always)
    for (int i = t; i < m; i += 256) csr[base + i] = sorted[i];
}

// ---------------- weight prep: wt[n][k] = bf16([Wl|Wr]^T) ----------------
__global__ void prep_w_kernel(const float* __restrict__ wl, const float* __restrict__ wr,
                              unsigned short* __restrict__ wt, int HALF, int K) {
    int idx = blockIdx.x * 256 + threadIdx.x;
    int total = 2 * HALF * K;
    if (idx >= total) return;
    int n = idx / K, k = idx % K;
    float v = (n < HALF) ? wl[(size_t)k * HALF + n] : wr[(size_t)k * HALF + (n - HALF)];
    wt[idx] = bf16_rne(v);
}

// ---------------- MFMA transform ----------------
// out: ybuf[node][HALF] bf16 (cols<HALF), rbuf[node][HALF] fp32 (+bias).
// K=128. Block = 4 waves -> 64-node x 64-col tile. grid.y = CO/64.
template <int CO, bool BF16IN>
__global__ __launch_bounds__(256) void transform_mfma_kernel(
        const void* __restrict__ xin, const unsigned short* __restrict__ wt,
        const float* __restrict__ bias, unsigned short* __restrict__ ybuf,
        float* __restrict__ rbuf, int n) {
    constexpr int HALF = CO / 2;
    constexpr int LDW = 136;   // 128 + 8 pad
    __shared__ unsigned short Xs[64][LDW];
    __shared__ unsigned short Ws[64][LDW];

    const int t = threadIdx.x;
    const int node0 = blockIdx.x * 64;
    const int gy = blockIdx.y;

    if (BF16IN) {
        const unsigned short* xb = (const unsigned short*)xin;
        for (int e = t; e < 64 * 16; e += 256) {
            int nd = e >> 4, c8 = e & 15;
            int node = node0 + nd;
            int4 v = (node < n) ? ((const int4*)(xb + (size_t)node * 128))[c8]
                                : make_int4(0, 0, 0, 0);
            *(int4*)&Xs[nd][c8 * 8] = v;
        }
    } else {
        const float* xf = (const float*)xin;
        for (int e = t; e < 64 * 32; e += 256) {
            int nd = e >> 5, c4 = e & 31;
            int node = node0 + nd;
            float4 v = (node < n) ? ((const float4*)xf)[(size_t)node * 32 + c4]
                                  : make_float4(0.f, 0.f, 0.f, 0.f);
            us4 p;
            p.x = bf16_rne(v.x); p.y = bf16_rne(v.y); p.z = bf16_rne(v.z); p.w = bf16_rne(v.w);
            *(us4*)&Xs[nd][c4 * 4] = p;
        }
    }
    for (int e = t; e < 64 * 16; e += 256) {
        int nd = e >> 4, c8 = e & 15;
        int4 v = ((const int4*)(wt + ((size_t)(gy * 64 + nd)) * 128))[c8];
        *(int4*)&Ws[nd][c8 * 8] = v;
    }
    __syncthreads();

    const int lane = t & 63, wave = t >> 6;
    const int wm = (wave & 1) * 32, wn = (wave >> 1) * 32;
    const int ml = wm + (lane & 31);
    const int nl = wn + (lane & 31);
    const int koff = (lane >> 5) * 8;

    f32x16 acc;
#pragma unroll
    for (int r = 0; r < 16; r++) acc[r] = 0.f;

#pragma unroll
    for (int kk = 0; kk < 8; kk++) {
        bf16x8 a = *(const bf16x8*)&Xs[ml][kk * 16 + koff];
        bf16x8 b = *(const bf16x8*)&Ws[nl][kk * 16 + koff];
        acc = __builtin_amdgcn_mfma_f32_32x32x16_bf16(a, b, acc, 0, 0, 0);
    }

    const int col = gy * 64 + wn + (lane & 31);
    if (col < HALF) {
#pragma unroll
        for (int r = 0; r < 16; r++) {
            int row = (r & 3) + 8 * (r >> 2) + 4 * (lane >> 5);
            int node = node0 + wm + row;
            if (node < n) ybuf[(size_t)node * HALF + col] = bf16_rne(acc[r]);
        }
    } else {
        const float bj = bias[col - HALF];
#pragma unroll
        for (int r = 0; r < 16; r++) {
            int row = (r & 3) + 8 * (r >> 2) + 4 * (lane >> 5);
            int node = node0 + wm + row;
            if (node < n) rbuf[(size_t)node * HALF + (col - HALF)] = acc[r] + bj;
        }
    }
}

// ---------------- gather + mean + add-root + L2norm, D=128 ----------------
template <bool OUTBF16>
__global__ __launch_bounds__(256) void gather128_kernel(
        const unsigned short* __restrict__ y, const float* __restrict__ rr,
        const int* __restrict__ rowoff, const unsigned short* __restrict__ csr,
        void* __restrict__ out, int n) {
    const int wave = threadIdx.x >> 6;
    const int lane = threadIdx.x & 63;
    const int node = blockIdx.x * 4 + wave;
    if (node >= n) return;

    const int off = rowoff[node];
    const int end = rowoff[node + 1];
    const int deg = end - off;

    float2 acc = make_float2(0.f, 0.f);
    for (int k0 = 0; k0 < deg; k0 += 8) {
        int idx[8];
#pragma unroll
        for (int i = 0; i < 8; i++) {
            int kk = off + k0 + i;
            idx[i] = csr[kk < end ? kk : end - 1];
        }
        unsigned v[8];
#pragma unroll
        for (int i = 0; i < 8; i++)
            v[i] = *(const unsigned*)(y + (size_t)idx[i] * 128 + 2 * lane);
#pragma unroll
        for (int i = 0; i < 8; i++)
            if (k0 + i < deg) {
                acc.x += bf16_to_f32((unsigned short)(v[i] & 0xffff));
                acc.y += bf16_to_f32((unsigned short)(v[i] >> 16));
            }
    }
    float im = 1.0f / fmaxf((float)deg, 1.0f);
    float2 rv = *(const float2*)(rr + (size_t)node * 128 + 2 * lane);
    float2 v = make_float2(acc.x * im + rv.x, acc.y * im + rv.y);
    float s = v.x * v.x + v.y * v.y;
#pragma unroll
    for (int m = 32; m >= 1; m >>= 1) s += __shfl_xor(s, m, 64);
    float rn = 1.0f / fmaxf(sqrtf(s), 1e-12f);
    v.x *= rn; v.y *= rn;
    if (OUTBF16) {
        unsigned pk = (unsigned)bf16_rne(v.x) | ((unsigned)bf16_rne(v.y) << 16);
        *(unsigned*)((unsigned short*)out + (size_t)node * 128 + 2 * lane) = pk;
    } else {
        *(float2*)((float*)out + (size_t)node * 128 + 2 * lane) = v;
    }
}

// ---------------- gather + mean + add-root + L2norm, D=64, fp32 out ----------------
__global__ __launch_bounds__(256) void gather64_kernel(
        const unsigned short* __restrict__ y, const float* __restrict__ rr,
        const int* __restrict__ rowoff, const unsigned short* __restrict__ csr,
        float* __restrict__ out, int n) {
    const int wave = threadIdx.x >> 6;
    const int lane = threadIdx.x & 63;
    const int node = blockIdx.x * 4 + wave;
    if (node >= n) return;

    const int off = rowoff[node];
    const int end = rowoff[node + 1];
    const int deg = end - off;

    float acc = 0.f;
    for (int k0 = 0; k0 < deg; k0 += 8) {
        int idx[8];
#pragma unroll
        for (int i = 0; i < 8; i++) {
            int kk = off + k0 + i;
            idx[i] = csr[kk < end ? kk : end - 1];
        }
        unsigned short v[8];
#pragma unroll
        for (int i = 0; i < 8; i++)
            v[i] = y[(size_t)idx[i] * 64 + lane];
#pragma unroll
        for (int i = 0; i < 8; i++)
            if (k0 + i < deg) acc += bf16_to_f32(v[i]);
    }
    float im = 1.0f / fmaxf((float)deg, 1.0f);
    float r = rr[(size_t)node * 64 + lane];
    float v = acc * im + r;
    float s = v * v;
#pragma unroll
    for (int m = 32; m >= 1; m >>= 1) s += __shfl_xor(s, m, 64);
    float rn = 1.0f / fmaxf(sqrtf(s), 1e-12f);
    out[(size_t)node * 64 + lane] = v * rn;
}

extern "C" void kernel_launch(void* const* d_in, const int* in_sizes, int n_in,
                              void* d_out, int out_size, void* d_ws, size_t ws_size,
                              hipStream_t stream) {
    const float* x   = (const float*)d_in[0];
    const int*   ei  = (const int*)d_in[1];   // [2, E] int32
    const float* w1l = (const float*)d_in[2];
    const float* b1  = (const float*)d_in[3];
    const float* w1r = (const float*)d_in[4];
    const float* w2l = (const float*)d_in[5];
    const float* b2  = (const float*)d_in[6];
    const float* w2r = (const float*)d_in[7];
    float* out = (float*)d_out;

    const int* src = ei;
    const int* dst = ei + EE;

    char* ws = (char*)d_ws;
    auto align = [](size_t v) { return (v + 255) & ~(size_t)255; };
    int*   deg    = (int*)ws;                 size_t o = align((size_t)NN * 4);
    int*   rowoff = (int*)(ws + o);           o += align((size_t)(NN + 1) * 4);
    int*   bcur   = (int*)(ws + o);           o += align((size_t)NB * 4);
    int*   bsum   = (int*)(ws + o);           o += align((size_t)NB * 4);
    int*   rec    = (int*)(ws + o);           o += align((size_t)NB * CAP * 4);     // 4.8 MB
    unsigned short* csr = (unsigned short*)(ws + o); o += align((size_t)EE * 2);    // 1.6 MB
    unsigned short* wt1 = (unsigned short*)(ws + o); o += align((size_t)256 * 128 * 2);
    unsigned short* wt2 = (unsigned short*)(ws + o); o += align((size_t)128 * 128 * 2);
    unsigned short* y1  = (unsigned short*)(ws + o); o += align((size_t)NN * 128 * 2);
    float*          r1  = (float*)(ws + o);          o += align((size_t)NN * 128 * 4);
    unsigned short* h1  = (unsigned short*)(ws + o); o += align((size_t)NN * 128 * 2);
    unsigned short* y2  = (unsigned short*)(ws + o); o += align((size_t)NN * 64 * 2);
    float*          r2  = (float*)(ws + o);          o += align((size_t)NN * 64 * 4);

    // ---- build CSR (bucketed counting sort) ----
    hipMemsetAsync(bcur, 0, (size_t)NB * 4, stream);
    bin_kernel<<<(EE + 255) / 256, 256, 0, stream>>>(src, dst, bcur, rec, EE);
    bucket_deg_kernel<<<NB, 256, 0, stream>>>(rec, bcur, deg, NN);
    scan1_kernel<<<NB, 256, 0, stream>>>(deg, bsum, NN);
    scan2_kernel<<<1, 256, 0, stream>>>(bsum, NB);
    scan3_kernel<<<NB, 256, 0, stream>>>(deg, bsum, rowoff, NN);
    place_kernel<<<NB, 256, 0, stream>>>(rec, bcur, rowoff, csr, NN);

    // ---- weight prep (bf16 transposed, [Wl|Wr] packed) ----
    prep_w_kernel<<<(256 * 128 + 255) / 256, 256, 0, stream>>>(w1l, w1r, wt1, 128, 128);
    prep_w_kernel<<<(128 * 128 + 255) / 256, 256, 0, stream>>>(w2l, w2r, wt2, 64, 128);

    // ---- layer 1: MFMA transform (y1 bf16, r1 fp32) then gather+norm -> h1 bf16 ----
    transform_mfma_kernel<256, false><<<dim3((NN + 63) / 64, 4), 256, 0, stream>>>(
        x, wt1, b1, y1, r1, NN);
    gather128_kernel<true><<<(NN + 3) / 4, 256, 0, stream>>>(y1, r1, rowoff, csr, h1, NN);

    // ---- layer 2: bf16-input transform then gather+norm -> out fp32 ----
    transform_mfma_kernel<128, true><<<dim3((NN + 63) / 64, 2), 256, 0, stream>>>(
        h1, wt2, b2, y2, r2, NN);
    gather64_kernel<<<(NN + 3) / 4, 256, 0, stream>>>(y2, r2, rowoff, csr, out, NN);
}

// Round 8
// 227.103 us; speedup vs baseline: 2.9574x; 2.9574x over previous
//
#include <hip/hip_runtime.h>
#include <math.h>

#define NN 50000
#define EE 800000
#define NB 196     // ceil(NN/256) : scan blocks AND coarse buckets (256 nodes each)
#define CAP 6144   // bucket capacity (mean 4081, sigma~64)

typedef __attribute__((ext_vector_type(8))) short bf16x8;
typedef __attribute__((ext_vector_type(16))) float f32x16;
typedef __attribute__((ext_vector_type(4))) unsigned short us4;

__device__ inline unsigned short bf16_rne(float f) {
    union { float f; unsigned u; } a; a.f = f;
    unsigned u = a.u;
    u += 0x7fff + ((u >> 16) & 1);
    return (unsigned short)(u >> 16);
}
__device__ inline float bf16_to_f32(unsigned short u) {
    union { unsigned u; float f; } a; a.u = ((unsigned)u) << 16;
    return a.f;
}

// ---------------- CSR build: bucketed counting sort ----------------
// pass 1: block-local LDS histogram -> one global reservation atomic per bucket
//         per block -> scatter records into private reserved ranges.
__global__ __launch_bounds__(1024) void bin_kernel(
        const int* __restrict__ src, const int* __restrict__ dst,
        int* __restrict__ gcur, int* __restrict__ rec, int E) {
    __shared__ int hist[NB];
    __shared__ int cur[NB];
    const int t = threadIdx.x;
    const int per = (E + gridDim.x - 1) / gridDim.x;
    const int lo = blockIdx.x * per;
    const int hi = min(lo + per, E);

    for (int i = t; i < NB; i += 1024) hist[i] = 0;
    __syncthreads();
    for (int e = lo + t; e < hi; e += 1024)
        atomicAdd(&hist[dst[e] >> 8], 1);
    __syncthreads();
    for (int i = t; i < NB; i += 1024)
        cur[i] = atomicAdd(&gcur[i], hist[i]);   // block-level reservation
    __syncthreads();
    for (int e = lo + t; e < hi; e += 1024) {
        int d = dst[e], s = src[e];
        int cb = d >> 8;
        int p = atomicAdd(&cur[cb], 1);          // LDS cursor
        if (p < CAP) rec[(size_t)cb * CAP + p] = ((d & 255) << 16) | s;
    }
}

// pass 2a: per-bucket LDS histogram -> deg (no global atomics, coalesced write)
__global__ __launch_bounds__(256) void bucket_deg_kernel(
        const int* __restrict__ rec, const int* __restrict__ bcur,
        int* __restrict__ deg, int n) {
    __shared__ int cnt[256];
    const int cb = blockIdx.x, t = threadIdx.x;
    cnt[t] = 0;
    __syncthreads();
    int m = bcur[cb]; if (m > CAP) m = CAP;
    const int* r = rec + (size_t)cb * CAP;
    for (int i = t; i < m; i += 256) atomicAdd(&cnt[r[i] >> 16], 1);
    __syncthreads();
    int node = cb * 256 + t;
    if (node < n) deg[node] = cnt[t];
}

// scan phase 1: per-block sums of deg
__global__ void scan1_kernel(const int* __restrict__ deg, int* __restrict__ bsum, int n) {
    __shared__ int s[256];
    int t = threadIdx.x;
    int i = blockIdx.x * 256 + t;
    s[t] = (i < n) ? deg[i] : 0;
    __syncthreads();
    for (int ofs = 128; ofs > 0; ofs >>= 1) {
        if (t < ofs) s[t] += s[t + ofs];
        __syncthreads();
    }
    if (t == 0) bsum[blockIdx.x] = s[0];
}

// scan phase 2: exclusive scan of block sums
__global__ void scan2_kernel(int* __restrict__ bsum, int nb) {
    __shared__ int s[256];
    int t = threadIdx.x;
    s[t] = (t < nb) ? bsum[t] : 0;
    __syncthreads();
    for (int ofs = 1; ofs < 256; ofs <<= 1) {
        int v = s[t];
        int a = (t >= ofs) ? s[t - ofs] : 0;
        __syncthreads();
        s[t] = v + a;
        __syncthreads();
    }
    if (t < nb) bsum[t] = (t == 0) ? 0 : s[t - 1];
}

// scan phase 3: in-block exclusive scan + block offset -> rowoff
__global__ void scan3_kernel(const int* __restrict__ deg, const int* __restrict__ bsum,
                             int* __restrict__ rowoff, int n) {
    __shared__ int s[256];
    int t = threadIdx.x;
    int i = blockIdx.x * 256 + t;
    int d = (i < n) ? deg[i] : 0;
    s[t] = d;
    __syncthreads();
    for (int ofs = 1; ofs < 256; ofs <<= 1) {
        int v = s[t];
        int a = (t >= ofs) ? s[t - ofs] : 0;
        __syncthreads();
        s[t] = v + a;
        __syncthreads();
    }
    int excl = s[t] - d + bsum[blockIdx.x];
    if (i < n) rowoff[i] = excl;
    if (i == n - 1) rowoff[n] = excl + d;
}

// pass 2b: per-bucket LDS counting sort -> contiguous coalesced csr segment write
__global__ __launch_bounds__(256) void place_kernel(
        const int* __restrict__ rec, const int* __restrict__ bcur,
        const int* __restrict__ rowoff, unsigned short* __restrict__ csr, int n) {
    __shared__ int cnt[256];
    __shared__ int cur[256];
    __shared__ unsigned short sorted[CAP];
    const int cb = blockIdx.x, t = threadIdx.x;
    int m = bcur[cb]; if (m > CAP) m = CAP;
    const int* r = rec + (size_t)cb * CAP;

    cnt[t] = 0;
    __syncthreads();
    for (int i = t; i < m; i += 256) atomicAdd(&cnt[r[i] >> 16], 1);
    __syncthreads();
    int orig = cnt[t];
    for (int ofs = 1; ofs < 256; ofs <<= 1) {
        int v = cnt[t];
        int a = (t >= ofs) ? cnt[t - ofs] : 0;
        __syncthreads();
        cnt[t] = v + a;
        __syncthreads();
    }
    cur[t] = cnt[t] - orig;
    __syncthreads();
    for (int i = t; i < m; i += 256) {
        int rr = r[i];
        int pos = atomicAdd(&cur[rr >> 16], 1);
        sorted[pos] = (unsigned short)(rr & 0xffff);
    }
    __syncthreads();
    const int base = rowoff[cb * 256];
    for (int i = t; i < m; i += 256) csr[base + i] = sorted[i];
}

// ---------------- weight prep: wt[n][k] = bf16([Wl|Wr]^T) ----------------
__global__ void prep_w_kernel(const float* __restrict__ wl, const float* __restrict__ wr,
                              unsigned short* __restrict__ wt, int HALF, int K) {
    int idx = blockIdx.x * 256 + threadIdx.x;
    int total = 2 * HALF * K;
    if (idx >= total) return;
    int n = idx / K, k = idx % K;
    float v = (n < HALF) ? wl[(size_t)k * HALF + n] : wr[(size_t)k * HALF + (n - HALF)];
    wt[idx] = bf16_rne(v);
}

// ---------------- MFMA transform ----------------
template <int CO, bool BF16IN>
__global__ __launch_bounds__(256) void transform_mfma_kernel(
        const void* __restrict__ xin, const unsigned short* __restrict__ wt,
        const float* __restrict__ bias, unsigned short* __restrict__ ybuf,
        float* __restrict__ rbuf, int n) {
    constexpr int HALF = CO / 2;
    constexpr int LDW = 136;
    __shared__ unsigned short Xs[64][LDW];
    __shared__ unsigned short Ws[64][LDW];

    const int t = threadIdx.x;
    const int node0 = blockIdx.x * 64;
    const int gy = blockIdx.y;

    if (BF16IN) {
        const unsigned short* xb = (const unsigned short*)xin;
        for (int e = t; e < 64 * 16; e += 256) {
            int nd = e >> 4, c8 = e & 15;
            int node = node0 + nd;
            int4 v = (node < n) ? ((const int4*)(xb + (size_t)node * 128))[c8]
                                : make_int4(0, 0, 0, 0);
            *(int4*)&Xs[nd][c8 * 8] = v;
        }
    } else {
        const float* xf = (const float*)xin;
        for (int e = t; e < 64 * 32; e += 256) {
            int nd = e >> 5, c4 = e & 31;
            int node = node0 + nd;
            float4 v = (node < n) ? ((const float4*)xf)[(size_t)node * 32 + c4]
                                  : make_float4(0.f, 0.f, 0.f, 0.f);
            us4 p;
            p.x = bf16_rne(v.x); p.y = bf16_rne(v.y); p.z = bf16_rne(v.z); p.w = bf16_rne(v.w);
            *(us4*)&Xs[nd][c4 * 4] = p;
        }
    }
    for (int e = t; e < 64 * 16; e += 256) {
        int nd = e >> 4, c8 = e & 15;
        int4 v = ((const int4*)(wt + ((size_t)(gy * 64 + nd)) * 128))[c8];
        *(int4*)&Ws[nd][c8 * 8] = v;
    }
    __syncthreads();

    const int lane = t & 63, wave = t >> 6;
    const int wm = (wave & 1) * 32, wn = (wave >> 1) * 32;
    const int ml = wm + (lane & 31);
    const int nl = wn + (lane & 31);
    const int koff = (lane >> 5) * 8;

    f32x16 acc;
#pragma unroll
    for (int r = 0; r < 16; r++) acc[r] = 0.f;

#pragma unroll
    for (int kk = 0; kk < 8; kk++) {
        bf16x8 a = *(const bf16x8*)&Xs[ml][kk * 16 + koff];
        bf16x8 b = *(const bf16x8*)&Ws[nl][kk * 16 + koff];
        acc = __builtin_amdgcn_mfma_f32_32x32x16_bf16(a, b, acc, 0, 0, 0);
    }

    const int col = gy * 64 + wn + (lane & 31);
    if (col < HALF) {
#pragma unroll
        for (int r = 0; r < 16; r++) {
            int row = (r & 3) + 8 * (r >> 2) + 4 * (lane >> 5);
            int node = node0 + wm + row;
            if (node < n) ybuf[(size_t)node * HALF + col] = bf16_rne(acc[r]);
        }
    } else {
        const float bj = bias[col - HALF];
#pragma unroll
        for (int r = 0; r < 16; r++) {
            int row = (r & 3) + 8 * (r >> 2) + 4 * (lane >> 5);
            int node = node0 + wm + row;
            if (node < n) rbuf[(size_t)node * HALF + (col - HALF)] = acc[r] + bj;
        }
    }
}

// ---------------- gather + mean + add-root + L2norm, D=128 ----------------
template <bool OUTBF16>
__global__ __launch_bounds__(256) void gather128_kernel(
        const unsigned short* __restrict__ y, const float* __restrict__ rr,
        const int* __restrict__ rowoff, const unsigned short* __restrict__ csr,
        void* __restrict__ out, int n) {
    const int wave = threadIdx.x >> 6;
    const int lane = threadIdx.x & 63;
    const int node = blockIdx.x * 4 + wave;
    if (node >= n) return;

    const int off = rowoff[node];
    const int end = rowoff[node + 1];
    const int deg = end - off;

    float2 acc = make_float2(0.f, 0.f);
    for (int k0 = 0; k0 < deg; k0 += 8) {
        int idx[8];
#pragma unroll
        for (int i = 0; i < 8; i++) {
            int kk = off + k0 + i;
            idx[i] = csr[kk < end ? kk : end - 1];
        }
        unsigned v[8];
#pragma unroll
        for (int i = 0; i < 8; i++)
            v[i] = *(const unsigned*)(y + (size_t)idx[i] * 128 + 2 * lane);
#pragma unroll
        for (int i = 0; i < 8; i++)
            if (k0 + i < deg) {
                acc.x += bf16_to_f32((unsigned short)(v[i] & 0xffff));
                acc.y += bf16_to_f32((unsigned short)(v[i] >> 16));
            }
    }
    float im = 1.0f / fmaxf((float)deg, 1.0f);
    float2 rv = *(const float2*)(rr + (size_t)node * 128 + 2 * lane);
    float2 v = make_float2(acc.x * im + rv.x, acc.y * im + rv.y);
    float s = v.x * v.x + v.y * v.y;
#pragma unroll
    for (int m = 32; m >= 1; m >>= 1) s += __shfl_xor(s, m, 64);
    float rn = 1.0f / fmaxf(sqrtf(s), 1e-12f);
    v.x *= rn; v.y *= rn;
    if (OUTBF16) {
        unsigned pk = (unsigned)bf16_rne(v.x) | ((unsigned)bf16_rne(v.y) << 16);
        *(unsigned*)((unsigned short*)out + (size_t)node * 128 + 2 * lane) = pk;
    } else {
        *(float2*)((float*)out + (size_t)node * 128 + 2 * lane) = v;
    }
}

// ---------------- gather + mean + add-root + L2norm, D=64, fp32 out ----------------
__global__ __launch_bounds__(256) void gather64_kernel(
        const unsigned short* __restrict__ y, const float* __restrict__ rr,
        const int* __restrict__ rowoff, const unsigned short* __restrict__ csr,
        float* __restrict__ out, int n) {
    const int wave = threadIdx.x >> 6;
    const int lane = threadIdx.x & 63;
    const int node = blockIdx.x * 4 + wave;
    if (node >= n) return;

    const int off = rowoff[node];
    const int end = rowoff[node + 1];
    const int deg = end - off;

    float acc = 0.f;
    for (int k0 = 0; k0 < deg; k0 += 8) {
        int idx[8];
#pragma unroll
        for (int i = 0; i < 8; i++) {
            int kk = off + k0 + i;
            idx[i] = csr[kk < end ? kk : end - 1];
        }
        unsigned short v[8];
#pragma unroll
        for (int i = 0; i < 8; i++)
            v[i] = y[(size_t)idx[i] * 64 + lane];
#pragma unroll
        for (int i = 0; i < 8; i++)
            if (k0 + i < deg) acc += bf16_to_f32(v[i]);
    }
    float im = 1.0f / fmaxf((float)deg, 1.0f);
    float r = rr[(size_t)node * 64 + lane];
    float v = acc * im + r;
    float s = v * v;
#pragma unroll
    for (int m = 32; m >= 1; m >>= 1) s += __shfl_xor(s, m, 64);
    float rn = 1.0f / fmaxf(sqrtf(s), 1e-12f);
    out[(size_t)node * 64 + lane] = v * rn;
}

extern "C" void kernel_launch(void* const* d_in, const int* in_sizes, int n_in,
                              void* d_out, int out_size, void* d_ws, size_t ws_size,
                              hipStream_t stream) {
    const float* x   = (const float*)d_in[0];
    const int*   ei  = (const int*)d_in[1];   // [2, E] int32
    const float* w1l = (const float*)d_in[2];
    const float* b1  = (const float*)d_in[3];
    const float* w1r = (const float*)d_in[4];
    const float* w2l = (const float*)d_in[5];
    const float* b2  = (const float*)d_in[6];
    const float* w2r = (const float*)d_in[7];
    float* out = (float*)d_out;

    const int* src = ei;
    const int* dst = ei + EE;

    char* ws = (char*)d_ws;
    auto align = [](size_t v) { return (v + 255) & ~(size_t)255; };
    int*   deg    = (int*)ws;                 size_t o = align((size_t)NN * 4);
    int*   rowoff = (int*)(ws + o);           o += align((size_t)(NN + 1) * 4);
    int*   bcur   = (int*)(ws + o);           o += align((size_t)NB * 4);
    int*   bsum   = (int*)(ws + o);           o += align((size_t)NB * 4);
    int*   rec    = (int*)(ws + o);           o += align((size_t)NB * CAP * 4);     // 4.8 MB
    unsigned short* csr = (unsigned short*)(ws + o); o += align((size_t)EE * 2);    // 1.6 MB
    unsigned short* wt1 = (unsigned short*)(ws + o); o += align((size_t)256 * 128 * 2);
    unsigned short* wt2 = (unsigned short*)(ws + o); o += align((size_t)128 * 128 * 2);
    unsigned short* y1  = (unsigned short*)(ws + o); o += align((size_t)NN * 128 * 2);
    float*          r1  = (float*)(ws + o);          o += align((size_t)NN * 128 * 4);
    unsigned short* h1  = (unsigned short*)(ws + o); o += align((size_t)NN * 128 * 2);
    unsigned short* y2  = (unsigned short*)(ws + o); o += align((size_t)NN * 64 * 2);
    float*          r2  = (float*)(ws + o);          o += align((size_t)NN * 64 * 4);

    // ---- build CSR (bucketed counting sort, block-aggregated reservations) ----
    hipMemsetAsync(bcur, 0, (size_t)NB * 4, stream);
    bin_kernel<<<128, 1024, 0, stream>>>(src, dst, bcur, rec, EE);
    bucket_deg_kernel<<<NB, 256, 0, stream>>>(rec, bcur, deg, NN);
    scan1_kernel<<<NB, 256, 0, stream>>>(deg, bsum, NN);
    scan2_kernel<<<1, 256, 0, stream>>>(bsum, NB);
    scan3_kernel<<<NB, 256, 0, stream>>>(deg, bsum, rowoff, NN);
    place_kernel<<<NB, 256, 0, stream>>>(rec, bcur, rowoff, csr, NN);

    // ---- weight prep (bf16 transposed, [Wl|Wr] packed) ----
    prep_w_kernel<<<(256 * 128 + 255) / 256, 256, 0, stream>>>(w1l, w1r, wt1, 128, 128);
    prep_w_kernel<<<(128 * 128 + 255) / 256, 256, 0, stream>>>(w2l, w2r, wt2, 64, 128);

    // ---- layer 1: MFMA transform (y1 bf16, r1 fp32) then gather+norm -> h1 bf16 ----
    transform_mfma_kernel<256, false><<<dim3((NN + 63) / 64, 4), 256, 0, stream>>>(
        x, wt1, b1, y1, r1, NN);
    gather128_kernel<true><<<(NN + 3) / 4, 256, 0, stream>>>(y1, r1, rowoff, csr, h1, NN);

    // ---- layer 2: bf16-input transform then gather+norm -> out fp32 ----
    transform_mfma_kernel<128, true><<<dim3((NN + 63) / 64, 2), 256, 0, stream>>>(
        h1, wt2, b2, y2, r2, NN);
    gather64_kernel<<<(NN + 3) / 4, 256, 0, stream>>>(y2, r2, rowoff, csr, out, NN);
}

// Round 9
// 220.503 us; speedup vs baseline: 3.0459x; 1.0299x over previous
//
#include <hip/hip_runtime.h>
#include <math.h>

#define NN 50000
#define EE 800000
#define NB 196     // ceil(NN/256) : scan blocks AND coarse buckets (256 nodes each)
#define CAP 6144   // bucket capacity (mean 4081, sigma~64)

typedef __attribute__((ext_vector_type(8))) short bf16x8;
typedef __attribute__((ext_vector_type(16))) float f32x16;
typedef __attribute__((ext_vector_type(4))) unsigned short us4;

__device__ inline unsigned short bf16_rne(float f) {
    union { float f; unsigned u; } a; a.f = f;
    unsigned u = a.u;
    u += 0x7fff + ((u >> 16) & 1);
    return (unsigned short)(u >> 16);
}
__device__ inline float bf16_lo(unsigned v) {
    union { unsigned u; float f; } a; a.u = v << 16;
    return a.f;
}
__device__ inline float bf16_hi(unsigned v) {
    union { unsigned u; float f; } a; a.u = v & 0xffff0000u;
    return a.f;
}

// ---------------- CSR build: bucketed counting sort ----------------
__global__ __launch_bounds__(1024) void bin_kernel(
        const int* __restrict__ src, const int* __restrict__ dst,
        int* __restrict__ gcur, int* __restrict__ rec, int E) {
    __shared__ int hist[NB];
    __shared__ int cur[NB];
    const int t = threadIdx.x;
    const int per = (E + gridDim.x - 1) / gridDim.x;
    const int lo = blockIdx.x * per;
    const int hi = min(lo + per, E);

    for (int i = t; i < NB; i += 1024) hist[i] = 0;
    __syncthreads();
    for (int e = lo + t; e < hi; e += 1024)
        atomicAdd(&hist[dst[e] >> 8], 1);
    __syncthreads();
    for (int i = t; i < NB; i += 1024)
        cur[i] = atomicAdd(&gcur[i], hist[i]);   // block-level reservation
    __syncthreads();
    for (int e = lo + t; e < hi; e += 1024) {
        int d = dst[e], s = src[e];
        int cb = d >> 8;
        int p = atomicAdd(&cur[cb], 1);          // LDS cursor
        if (p < CAP) rec[(size_t)cb * CAP + p] = ((d & 255) << 16) | s;
    }
}

// per-bucket histogram -> deg, fused with block-sum -> bsum
__global__ __launch_bounds__(256) void bucket_deg_scan1_kernel(
        const int* __restrict__ rec, const int* __restrict__ bcur,
        int* __restrict__ deg, int* __restrict__ bsum, int n) {
    __shared__ int cnt[256];
    const int cb = blockIdx.x, t = threadIdx.x;
    cnt[t] = 0;
    __syncthreads();
    int m = bcur[cb]; if (m > CAP) m = CAP;
    const int* r = rec + (size_t)cb * CAP;
    for (int i = t; i < m; i += 256) atomicAdd(&cnt[r[i] >> 16], 1);
    __syncthreads();
    int node = cb * 256 + t;
    int d = cnt[t];
    if (node < n) deg[node] = d;
    __syncthreads();
    for (int ofs = 128; ofs > 0; ofs >>= 1) {
        if (t < ofs) cnt[t] += cnt[t + ofs];
        __syncthreads();
    }
    if (t == 0) bsum[cb] = cnt[0];
}

// exclusive scan of block sums
__global__ void scan2_kernel(int* __restrict__ bsum, int nb) {
    __shared__ int s[256];
    int t = threadIdx.x;
    s[t] = (t < nb) ? bsum[t] : 0;
    __syncthreads();
    for (int ofs = 1; ofs < 256; ofs <<= 1) {
        int v = s[t];
        int a = (t >= ofs) ? s[t - ofs] : 0;
        __syncthreads();
        s[t] = v + a;
        __syncthreads();
    }
    if (t < nb) bsum[t] = (t == 0) ? 0 : s[t - 1];
}

// in-block exclusive scan + block offset -> rowoff
__global__ void scan3_kernel(const int* __restrict__ deg, const int* __restrict__ bsum,
                             int* __restrict__ rowoff, int n) {
    __shared__ int s[256];
    int t = threadIdx.x;
    int i = blockIdx.x * 256 + t;
    int d = (i < n) ? deg[i] : 0;
    s[t] = d;
    __syncthreads();
    for (int ofs = 1; ofs < 256; ofs <<= 1) {
        int v = s[t];
        int a = (t >= ofs) ? s[t - ofs] : 0;
        __syncthreads();
        s[t] = v + a;
        __syncthreads();
    }
    int excl = s[t] - d + bsum[blockIdx.x];
    if (i < n) rowoff[i] = excl;
    if (i == n - 1) rowoff[n] = excl + d;
}

// per-bucket LDS counting sort -> contiguous coalesced csr segment write
__global__ __launch_bounds__(256) void place_kernel(
        const int* __restrict__ rec, const int* __restrict__ bcur,
        const int* __restrict__ rowoff, unsigned short* __restrict__ csr, int n) {
    __shared__ int cnt[256];
    __shared__ int cur[256];
    __shared__ unsigned short sorted[CAP];
    const int cb = blockIdx.x, t = threadIdx.x;
    int m = bcur[cb]; if (m > CAP) m = CAP;
    const int* r = rec + (size_t)cb * CAP;

    cnt[t] = 0;
    __syncthreads();
    for (int i = t; i < m; i += 256) atomicAdd(&cnt[r[i] >> 16], 1);
    __syncthreads();
    int orig = cnt[t];
    for (int ofs = 1; ofs < 256; ofs <<= 1) {
        int v = cnt[t];
        int a = (t >= ofs) ? cnt[t - ofs] : 0;
        __syncthreads();
        cnt[t] = v + a;
        __syncthreads();
    }
    cur[t] = cnt[t] - orig;
    __syncthreads();
    for (int i = t; i < m; i += 256) {
        int rr = r[i];
        int pos = atomicAdd(&cur[rr >> 16], 1);
        sorted[pos] = (unsigned short)(rr & 0xffff);
    }
    __syncthreads();
    const int base = rowoff[cb * 256];
    for (int i = t; i < m; i += 256) csr[base + i] = sorted[i];
}

// ---------------- weight prep: wt[n][k] = bf16([Wl|Wr]^T) ----------------
__global__ void prep_w_kernel(const float* __restrict__ wl, const float* __restrict__ wr,
                              unsigned short* __restrict__ wt, int HALF, int K) {
    int idx = blockIdx.x * 256 + threadIdx.x;
    int total = 2 * HALF * K;
    if (idx >= total) return;
    int n = idx / K, k = idx % K;
    float v = (n < HALF) ? wl[(size_t)k * HALF + n] : wr[(size_t)k * HALF + (n - HALF)];
    wt[idx] = bf16_rne(v);
}

// ---------------- MFMA transform ----------------
template <int CO, bool BF16IN>
__global__ __launch_bounds__(256) void transform_mfma_kernel(
        const void* __restrict__ xin, const unsigned short* __restrict__ wt,
        const float* __restrict__ bias, unsigned short* __restrict__ ybuf,
        float* __restrict__ rbuf, int n) {
    constexpr int HALF = CO / 2;
    constexpr int LDW = 136;
    __shared__ unsigned short Xs[64][LDW];
    __shared__ unsigned short Ws[64][LDW];

    const int t = threadIdx.x;
    const int node0 = blockIdx.x * 64;
    const int gy = blockIdx.y;

    if (BF16IN) {
        const unsigned short* xb = (const unsigned short*)xin;
        for (int e = t; e < 64 * 16; e += 256) {
            int nd = e >> 4, c8 = e & 15;
            int node = node0 + nd;
            int4 v = (node < n) ? ((const int4*)(xb + (size_t)node * 128))[c8]
                                : make_int4(0, 0, 0, 0);
            *(int4*)&Xs[nd][c8 * 8] = v;
        }
    } else {
        const float* xf = (const float*)xin;
        for (int e = t; e < 64 * 32; e += 256) {
            int nd = e >> 5, c4 = e & 31;
            int node = node0 + nd;
            float4 v = (node < n) ? ((const float4*)xf)[(size_t)node * 32 + c4]
                                  : make_float4(0.f, 0.f, 0.f, 0.f);
            us4 p;
            p.x = bf16_rne(v.x); p.y = bf16_rne(v.y); p.z = bf16_rne(v.z); p.w = bf16_rne(v.w);
            *(us4*)&Xs[nd][c4 * 4] = p;
        }
    }
    for (int e = t; e < 64 * 16; e += 256) {
        int nd = e >> 4, c8 = e & 15;
        int4 v = ((const int4*)(wt + ((size_t)(gy * 64 + nd)) * 128))[c8];
        *(int4*)&Ws[nd][c8 * 8] = v;
    }
    __syncthreads();

    const int lane = t & 63, wave = t >> 6;
    const int wm = (wave & 1) * 32, wn = (wave >> 1) * 32;
    const int ml = wm + (lane & 31);
    const int nl = wn + (lane & 31);
    const int koff = (lane >> 5) * 8;

    f32x16 acc;
#pragma unroll
    for (int r = 0; r < 16; r++) acc[r] = 0.f;

#pragma unroll
    for (int kk = 0; kk < 8; kk++) {
        bf16x8 a = *(const bf16x8*)&Xs[ml][kk * 16 + koff];
        bf16x8 b = *(const bf16x8*)&Ws[nl][kk * 16 + koff];
        acc = __builtin_amdgcn_mfma_f32_32x32x16_bf16(a, b, acc, 0, 0, 0);
    }

    const int col = gy * 64 + wn + (lane & 31);
    if (col < HALF) {
#pragma unroll
        for (int r = 0; r < 16; r++) {
            int row = (r & 3) + 8 * (r >> 2) + 4 * (lane >> 5);
            int node = node0 + wm + row;
            if (node < n) ybuf[(size_t)node * HALF + col] = bf16_rne(acc[r]);
        }
    } else {
        const float bj = bias[col - HALF];
#pragma unroll
        for (int r = 0; r < 16; r++) {
            int row = (r & 3) + 8 * (r >> 2) + 4 * (lane >> 5);
            int node = node0 + wm + row;
            if (node < n) rbuf[(size_t)node * HALF + (col - HALF)] = acc[r] + bj;
        }
    }
}

// ---------------- gather + mean + add-root + L2norm, D=128 ----------------
// Zero-row padding: OOB neighbors map to row n (zeroed) -> unconditional adds.
template <bool OUTBF16>
__global__ __launch_bounds__(256) void gather128_kernel(
        const unsigned short* __restrict__ y, const float* __restrict__ rr,
        const int* __restrict__ rowoff, const unsigned short* __restrict__ csr,
        void* __restrict__ out, int n) {
    const int wave = threadIdx.x >> 6;
    const int lane = threadIdx.x & 63;
    const int node = blockIdx.x * 4 + wave;
    if (node >= n) return;

    const int off = rowoff[node];
    const int end = rowoff[node + 1];
    const int deg = end - off;

    float2 acc = make_float2(0.f, 0.f);
    for (int k0 = 0; k0 < deg; k0 += 16) {
        int idx[16];
#pragma unroll
        for (int i = 0; i < 16; i++) {
            int kk = off + k0 + i;
            idx[i] = (kk < end) ? (int)csr[kk] : n;   // n = zero row
        }
        unsigned v[16];
#pragma unroll
        for (int i = 0; i < 16; i++)
            v[i] = *(const unsigned*)(y + (size_t)idx[i] * 128 + 2 * lane);
#pragma unroll
        for (int i = 0; i < 16; i++) {
            acc.x += bf16_lo(v[i]);
            acc.y += bf16_hi(v[i]);
        }
    }
    float im = 1.0f / fmaxf((float)deg, 1.0f);
    float2 rv = *(const float2*)(rr + (size_t)node * 128 + 2 * lane);
    float2 v = make_float2(acc.x * im + rv.x, acc.y * im + rv.y);
    float s = v.x * v.x + v.y * v.y;
#pragma unroll
    for (int m = 32; m >= 1; m >>= 1) s += __shfl_xor(s, m, 64);
    float rn = 1.0f / fmaxf(sqrtf(s), 1e-12f);
    v.x *= rn; v.y *= rn;
    if (OUTBF16) {
        unsigned pk = (unsigned)bf16_rne(v.x) | ((unsigned)bf16_rne(v.y) << 16);
        *(unsigned*)((unsigned short*)out + (size_t)node * 128 + 2 * lane) = pk;
    } else {
        *(float2*)((float*)out + (size_t)node * 128 + 2 * lane) = v;
    }
}

// ---------------- gather + mean + add-root + L2norm, D=64, fp32 out ----------------
// Split-wave: half 0 (lanes 0-31) handles even neighbors, half 1 odd ones.
// Each lane loads a uint (2 cols) -> 2 rows per VMEM instruction.
__global__ __launch_bounds__(256) void gather64_kernel(
        const unsigned short* __restrict__ y, const float* __restrict__ rr,
        const int* __restrict__ rowoff, const unsigned short* __restrict__ csr,
        float* __restrict__ out, int n) {
    const int wave = threadIdx.x >> 6;
    const int lane = threadIdx.x & 63;
    const int node = blockIdx.x * 4 + wave;
    if (node >= n) return;
    const int half = lane >> 5;
    const int l32 = lane & 31;

    const int off = rowoff[node];
    const int end = rowoff[node + 1];
    const int deg = end - off;
    const int P = (deg + 1) >> 1;   // neighbor pairs

    float2 acc = make_float2(0.f, 0.f);
    for (int p0 = 0; p0 < P; p0 += 8) {
        int idx[8];
#pragma unroll
        for (int i = 0; i < 8; i++) {
            int kk = off + 2 * (p0 + i) + half;
            idx[i] = (kk < end) ? (int)csr[kk] : n;   // n = zero row
        }
        unsigned v[8];
#pragma unroll
        for (int i = 0; i < 8; i++)
            v[i] = *(const unsigned*)(y + (size_t)idx[i] * 64 + 2 * l32);
#pragma unroll
        for (int i = 0; i < 8; i++) {
            acc.x += bf16_lo(v[i]);
            acc.y += bf16_hi(v[i]);
        }
    }
    // combine even/odd halves (lane L and L^32 hold the same columns)
    acc.x += __shfl_xor(acc.x, 32, 64);
    acc.y += __shfl_xor(acc.y, 32, 64);

    float im = 1.0f / fmaxf((float)deg, 1.0f);
    float2 rv = *(const float2*)(rr + (size_t)node * 64 + 2 * l32);
    float2 v = make_float2(acc.x * im + rv.x, acc.y * im + rv.y);
    float s = v.x * v.x + v.y * v.y;
#pragma unroll
    for (int m = 32; m >= 1; m >>= 1) s += __shfl_xor(s, m, 64);
    s *= 0.5f;   // both halves contributed identical copies
    float rn = 1.0f / fmaxf(sqrtf(s), 1e-12f);
    if (half == 0)
        *(float2*)(out + (size_t)node * 64 + 2 * l32) = make_float2(v.x * rn, v.y * rn);
}

extern "C" void kernel_launch(void* const* d_in, const int* in_sizes, int n_in,
                              void* d_out, int out_size, void* d_ws, size_t ws_size,
                              hipStream_t stream) {
    const float* x   = (const float*)d_in[0];
    const int*   ei  = (const int*)d_in[1];   // [2, E] int32
    const float* w1l = (const float*)d_in[2];
    const float* b1  = (const float*)d_in[3];
    const float* w1r = (const float*)d_in[4];
    const float* w2l = (const float*)d_in[5];
    const float* b2  = (const float*)d_in[6];
    const float* w2r = (const float*)d_in[7];
    float* out = (float*)d_out;

    const int* src = ei;
    const int* dst = ei + EE;

    char* ws = (char*)d_ws;
    auto align = [](size_t v) { return (v + 255) & ~(size_t)255; };
    int*   deg    = (int*)ws;                 size_t o = align((size_t)NN * 4);
    int*   rowoff = (int*)(ws + o);           o += align((size_t)(NN + 1) * 4);
    int*   bcur   = (int*)(ws + o);           o += align((size_t)NB * 4);
    int*   bsum   = (int*)(ws + o);           o += align((size_t)NB * 4);
    int*   rec    = (int*)(ws + o);           o += align((size_t)NB * CAP * 4);     // 4.8 MB
    unsigned short* csr = (unsigned short*)(ws + o); o += align((size_t)EE * 2);    // 1.6 MB
    unsigned short* wt1 = (unsigned short*)(ws + o); o += align((size_t)256 * 128 * 2);
    unsigned short* wt2 = (unsigned short*)(ws + o); o += align((size_t)128 * 128 * 2);
    unsigned short* y1  = (unsigned short*)(ws + o); o += align((size_t)(NN + 1) * 128 * 2);
    float*          r1  = (float*)(ws + o);          o += align((size_t)NN * 128 * 4);
    unsigned short* h1  = (unsigned short*)(ws + o); o += align((size_t)NN * 128 * 2);
    unsigned short* y2  = (unsigned short*)(ws + o); o += align((size_t)(NN + 1) * 64 * 2);
    float*          r2  = (float*)(ws + o);          o += align((size_t)NN * 64 * 4);

    // ---- build CSR (bucketed counting sort, block-aggregated reservations) ----
    hipMemsetAsync(bcur, 0, (size_t)NB * 4, stream);
    hipMemsetAsync(y1 + (size_t)NN * 128, 0, 256, stream);   // zero pad rows
    hipMemsetAsync(y2 + (size_t)NN * 64, 0, 128, stream);
    bin_kernel<<<128, 1024, 0, stream>>>(src, dst, bcur, rec, EE);
    bucket_deg_scan1_kernel<<<NB, 256, 0, stream>>>(rec, bcur, deg, bsum, NN);
    scan2_kernel<<<1, 256, 0, stream>>>(bsum, NB);
    scan3_kernel<<<NB, 256, 0, stream>>>(deg, bsum, rowoff, NN);
    place_kernel<<<NB, 256, 0, stream>>>(rec, bcur, rowoff, csr, NN);

    // ---- weight prep (bf16 transposed, [Wl|Wr] packed) ----
    prep_w_kernel<<<(256 * 128 + 255) / 256, 256, 0, stream>>>(w1l, w1r, wt1, 128, 128);
    prep_w_kernel<<<(128 * 128 + 255) / 256, 256, 0, stream>>>(w2l, w2r, wt2, 64, 128);

    // ---- layer 1: MFMA transform (y1 bf16, r1 fp32) then gather+norm -> h1 bf16 ----
    transform_mfma_kernel<256, false><<<dim3((NN + 63) / 64, 4), 256, 0, stream>>>(
        x, wt1, b1, y1, r1, NN);
    gather128_kernel<true><<<(NN + 3) / 4, 256, 0, stream>>>(y1, r1, rowoff, csr, h1, NN);

    // ---- layer 2: bf16-input transform then gather+norm -> out fp32 ----
    transform_mfma_kernel<128, true><<<dim3((NN + 63) / 64, 2), 256, 0, stream>>>(
        h1, wt2, b2, y2, r2, NN);
    gather64_kernel<<<(NN + 3) / 4, 256, 0, stream>>>(y2, r2, rowoff, csr, out, NN);
}

// Round 10
// 205.494 us; speedup vs baseline: 3.2684x; 1.0730x over previous
//
#include <hip/hip_runtime.h>
#include <math.h>

#define NN 50000
#define EE 800000
#define NB 196     // ceil(NN/256) : coarse buckets (256 nodes each)
#define CAP 6144   // bucket capacity (mean 4081, sigma~64)

typedef __attribute__((ext_vector_type(8))) short bf16x8;
typedef __attribute__((ext_vector_type(16))) float f32x16;
typedef __attribute__((ext_vector_type(4))) unsigned short us4;

__device__ inline unsigned short bf16_rne(float f) {
    union { float f; unsigned u; } a; a.f = f;
    unsigned u = a.u;
    u += 0x7fff + ((u >> 16) & 1);
    return (unsigned short)(u >> 16);
}
__device__ inline float bf16_lo(unsigned v) {
    union { unsigned u; float f; } a; a.u = v << 16;
    return a.f;
}
__device__ inline float bf16_hi(unsigned v) {
    union { unsigned u; float f; } a; a.u = v & 0xffff0000u;
    return a.f;
}

// ---------------- prep: weight bf16-transpose (both layers) + zero pads + zero bcur ----
// wt[n][k] = bf16(W^T). Layout: [wt1: 256*128][wt2: 128*128].
__global__ void prep_all_kernel(const float* __restrict__ w1l, const float* __restrict__ w1r,
                                const float* __restrict__ w2l, const float* __restrict__ w2r,
                                unsigned short* __restrict__ wt1, unsigned short* __restrict__ wt2,
                                unsigned short* __restrict__ y1pad, unsigned short* __restrict__ y2pad,
                                int* __restrict__ bcur) {
    int idx = blockIdx.x * 256 + threadIdx.x;
    if (idx < 32768) {                 // wt1: 2*128 x 128
        int n = idx >> 7, k = idx & 127;
        float v = (n < 128) ? w1l[(size_t)k * 128 + n] : w1r[(size_t)k * 128 + (n - 128)];
        wt1[idx] = bf16_rne(v);
    } else if (idx < 49152) {          // wt2: 2*64 x 128
        int j = idx - 32768;
        int n = j >> 7, k = j & 127;
        float v = (n < 64) ? w2l[(size_t)k * 64 + n] : w2r[(size_t)k * 64 + (n - 64)];
        wt2[j] = bf16_rne(v);
    } else {
        int j = idx - 49152;
        if (j < 128) y1pad[j] = 0;          // zero row at y1[NN]
        else if (j < 192) y2pad[j - 128] = 0; // zero row at y2[NN]
        else if (j < 192 + NB) bcur[j - 192] = 0;
    }
}

// ---------------- CSR build: bucketed counting sort ----------------
__global__ __launch_bounds__(1024) void bin_kernel(
        const int* __restrict__ src, const int* __restrict__ dst,
        int* __restrict__ gcur, int* __restrict__ rec, int E) {
    __shared__ int hist[NB];
    __shared__ int cur[NB];
    const int t = threadIdx.x;
    const int per = (E + gridDim.x - 1) / gridDim.x;
    const int lo = blockIdx.x * per;
    const int hi = min(lo + per, E);

    for (int i = t; i < NB; i += 1024) hist[i] = 0;
    __syncthreads();
    for (int e = lo + t; e < hi; e += 1024)
        atomicAdd(&hist[dst[e] >> 8], 1);
    __syncthreads();
    for (int i = t; i < NB; i += 1024)
        cur[i] = atomicAdd(&gcur[i], hist[i]);   // block-level reservation
    __syncthreads();
    for (int e = lo + t; e < hi; e += 1024) {
        int d = dst[e], s = src[e];
        int cb = d >> 8;
        int p = atomicAdd(&cur[cb], 1);          // LDS cursor
        if (p < CAP) rec[(size_t)cb * CAP + p] = ((d & 255) << 16) | s;
    }
}

// exclusive scan of bucket counts (bcur) -> bsum. nb <= 256.
__global__ void scan2_kernel(const int* __restrict__ bcur, int* __restrict__ bsum, int nb) {
    __shared__ int s[256];
    int t = threadIdx.x;
    s[t] = (t < nb) ? bcur[t] : 0;
    __syncthreads();
    for (int ofs = 1; ofs < 256; ofs <<= 1) {
        int v = s[t];
        int a = (t >= ofs) ? s[t - ofs] : 0;
        __syncthreads();
        s[t] = v + a;
        __syncthreads();
    }
    if (t < nb) bsum[t] = (t == 0) ? 0 : s[t - 1];
}

// per-bucket LDS counting sort -> rowoff + contiguous coalesced csr segment
__global__ __launch_bounds__(256) void place_kernel(
        const int* __restrict__ rec, const int* __restrict__ bcur,
        const int* __restrict__ bsum, int* __restrict__ rowoff,
        unsigned short* __restrict__ csr, int n) {
    __shared__ int cnt[256];
    __shared__ int cur[256];
    __shared__ unsigned short sorted[CAP];
    const int cb = blockIdx.x, t = threadIdx.x;
    int m = bcur[cb]; if (m > CAP) m = CAP;
    const int* r = rec + (size_t)cb * CAP;
    const int base = bsum[cb];

    cnt[t] = 0;
    __syncthreads();
    for (int i = t; i < m; i += 256) atomicAdd(&cnt[r[i] >> 16], 1);
    __syncthreads();
    int orig = cnt[t];
    for (int ofs = 1; ofs < 256; ofs <<= 1) {
        int v = cnt[t];
        int a = (t >= ofs) ? cnt[t - ofs] : 0;
        __syncthreads();
        cnt[t] = v + a;
        __syncthreads();
    }
    int excl = cnt[t] - orig;
    int node = cb * 256 + t;
    if (node < n) rowoff[node] = base + excl;
    if (node == n - 1) rowoff[n] = base + cnt[t];
    cur[t] = excl;
    __syncthreads();
    for (int i = t; i < m; i += 256) {
        int rr = r[i];
        int pos = atomicAdd(&cur[rr >> 16], 1);
        sorted[pos] = (unsigned short)(rr & 0xffff);
    }
    __syncthreads();
    for (int i = t; i < m; i += 256) csr[base + i] = sorted[i];
}

// ---------------- MFMA transform ----------------
template <int CO, bool BF16IN>
__global__ __launch_bounds__(256) void transform_mfma_kernel(
        const void* __restrict__ xin, const unsigned short* __restrict__ wt,
        const float* __restrict__ bias, unsigned short* __restrict__ ybuf,
        float* __restrict__ rbuf, int n) {
    constexpr int HALF = CO / 2;
    constexpr int LDW = 136;
    __shared__ unsigned short Xs[64][LDW];
    __shared__ unsigned short Ws[64][LDW];

    const int t = threadIdx.x;
    const int node0 = blockIdx.x * 64;
    const int gy = blockIdx.y;

    if (BF16IN) {
        const unsigned short* xb = (const unsigned short*)xin;
        for (int e = t; e < 64 * 16; e += 256) {
            int nd = e >> 4, c8 = e & 15;
            int node = node0 + nd;
            int4 v = (node < n) ? ((const int4*)(xb + (size_t)node * 128))[c8]
                                : make_int4(0, 0, 0, 0);
            *(int4*)&Xs[nd][c8 * 8] = v;
        }
    } else {
        const float* xf = (const float*)xin;
        for (int e = t; e < 64 * 32; e += 256) {
            int nd = e >> 5, c4 = e & 31;
            int node = node0 + nd;
            float4 v = (node < n) ? ((const float4*)xf)[(size_t)node * 32 + c4]
                                  : make_float4(0.f, 0.f, 0.f, 0.f);
            us4 p;
            p.x = bf16_rne(v.x); p.y = bf16_rne(v.y); p.z = bf16_rne(v.z); p.w = bf16_rne(v.w);
            *(us4*)&Xs[nd][c4 * 4] = p;
        }
    }
    for (int e = t; e < 64 * 16; e += 256) {
        int nd = e >> 4, c8 = e & 15;
        int4 v = ((const int4*)(wt + ((size_t)(gy * 64 + nd)) * 128))[c8];
        *(int4*)&Ws[nd][c8 * 8] = v;
    }
    __syncthreads();

    const int lane = t & 63, wave = t >> 6;
    const int wm = (wave & 1) * 32, wn = (wave >> 1) * 32;
    const int ml = wm + (lane & 31);
    const int nl = wn + (lane & 31);
    const int koff = (lane >> 5) * 8;

    f32x16 acc;
#pragma unroll
    for (int r = 0; r < 16; r++) acc[r] = 0.f;

#pragma unroll
    for (int kk = 0; kk < 8; kk++) {
        bf16x8 a = *(const bf16x8*)&Xs[ml][kk * 16 + koff];
        bf16x8 b = *(const bf16x8*)&Ws[nl][kk * 16 + koff];
        acc = __builtin_amdgcn_mfma_f32_32x32x16_bf16(a, b, acc, 0, 0, 0);
    }

    const int col = gy * 64 + wn + (lane & 31);
    if (col < HALF) {
#pragma unroll
        for (int r = 0; r < 16; r++) {
            int row = (r & 3) + 8 * (r >> 2) + 4 * (lane >> 5);
            int node = node0 + wm + row;
            if (node < n) ybuf[(size_t)node * HALF + col] = bf16_rne(acc[r]);
        }
    } else {
        const float bj = bias[col - HALF];
#pragma unroll
        for (int r = 0; r < 16; r++) {
            int row = (r & 3) + 8 * (r >> 2) + 4 * (lane >> 5);
            int node = node0 + wm + row;
            if (node < n) rbuf[(size_t)node * HALF + (col - HALF)] = acc[r] + bj;
        }
    }
}

// ---------------- gather + mean + add-root + L2norm, D=128 ----------------
template <bool OUTBF16>
__global__ __launch_bounds__(256) void gather128_kernel(
        const unsigned short* __restrict__ y, const float* __restrict__ rr,
        const int* __restrict__ rowoff, const unsigned short* __restrict__ csr,
        void* __restrict__ out, int n) {
    const int wave = threadIdx.x >> 6;
    const int lane = threadIdx.x & 63;
    const int node = blockIdx.x * 4 + wave;
    if (node >= n) return;

    const int off = rowoff[node];
    const int end = rowoff[node + 1];
    const int deg = end - off;

    float2 acc = make_float2(0.f, 0.f);
    for (int k0 = 0; k0 < deg; k0 += 16) {
        int idx[16];
#pragma unroll
        for (int i = 0; i < 16; i++) {
            int kk = off + k0 + i;
            idx[i] = (kk < end) ? (int)csr[kk] : n;   // n = zero row
        }
        unsigned v[16];
#pragma unroll
        for (int i = 0; i < 16; i++)
            v[i] = *(const unsigned*)(y + (size_t)idx[i] * 128 + 2 * lane);
#pragma unroll
        for (int i = 0; i < 16; i++) {
            acc.x += bf16_lo(v[i]);
            acc.y += bf16_hi(v[i]);
        }
    }
    float im = 1.0f / fmaxf((float)deg, 1.0f);
    float2 rv = *(const float2*)(rr + (size_t)node * 128 + 2 * lane);
    float2 v = make_float2(acc.x * im + rv.x, acc.y * im + rv.y);
    float s = v.x * v.x + v.y * v.y;
#pragma unroll
    for (int m = 32; m >= 1; m >>= 1) s += __shfl_xor(s, m, 64);
    float rn = 1.0f / fmaxf(sqrtf(s), 1e-12f);
    v.x *= rn; v.y *= rn;
    if (OUTBF16) {
        unsigned pk = (unsigned)bf16_rne(v.x) | ((unsigned)bf16_rne(v.y) << 16);
        *(unsigned*)((unsigned short*)out + (size_t)node * 128 + 2 * lane) = pk;
    } else {
        *(float2*)((float*)out + (size_t)node * 128 + 2 * lane) = v;
    }
}

// ---------------- gather + mean + add-root + L2norm, D=64, fp32 out ----------------
__global__ __launch_bounds__(256) void gather64_kernel(
        const unsigned short* __restrict__ y, const float* __restrict__ rr,
        const int* __restrict__ rowoff, const unsigned short* __restrict__ csr,
        float* __restrict__ out, int n) {
    const int wave = threadIdx.x >> 6;
    const int lane = threadIdx.x & 63;
    const int node = blockIdx.x * 4 + wave;
    if (node >= n) return;
    const int half = lane >> 5;
    const int l32 = lane & 31;

    const int off = rowoff[node];
    const int end = rowoff[node + 1];
    const int deg = end - off;
    const int P = (deg + 1) >> 1;   // neighbor pairs

    float2 acc = make_float2(0.f, 0.f);
    for (int p0 = 0; p0 < P; p0 += 8) {
        int idx[8];
#pragma unroll
        for (int i = 0; i < 8; i++) {
            int kk = off + 2 * (p0 + i) + half;
            idx[i] = (kk < end) ? (int)csr[kk] : n;   // n = zero row
        }
        unsigned v[8];
#pragma unroll
        for (int i = 0; i < 8; i++)
            v[i] = *(const unsigned*)(y + (size_t)idx[i] * 64 + 2 * l32);
#pragma unroll
        for (int i = 0; i < 8; i++) {
            acc.x += bf16_lo(v[i]);
            acc.y += bf16_hi(v[i]);
        }
    }
    acc.x += __shfl_xor(acc.x, 32, 64);
    acc.y += __shfl_xor(acc.y, 32, 64);

    float im = 1.0f / fmaxf((float)deg, 1.0f);
    float2 rv = *(const float2*)(rr + (size_t)node * 64 + 2 * l32);
    float2 v = make_float2(acc.x * im + rv.x, acc.y * im + rv.y);
    float s = v.x * v.x + v.y * v.y;
#pragma unroll
    for (int m = 32; m >= 1; m >>= 1) s += __shfl_xor(s, m, 64);
    s *= 0.5f;   // both halves hold identical copies
    float rn = 1.0f / fmaxf(sqrtf(s), 1e-12f);
    if (half == 0)
        *(float2*)(out + (size_t)node * 64 + 2 * l32) = make_float2(v.x * rn, v.y * rn);
}

extern "C" void kernel_launch(void* const* d_in, const int* in_sizes, int n_in,
                              void* d_out, int out_size, void* d_ws, size_t ws_size,
                              hipStream_t stream) {
    const float* x   = (const float*)d_in[0];
    const int*   ei  = (const int*)d_in[1];   // [2, E] int32
    const float* w1l = (const float*)d_in[2];
    const float* b1  = (const float*)d_in[3];
    const float* w1r = (const float*)d_in[4];
    const float* w2l = (const float*)d_in[5];
    const float* b2  = (const float*)d_in[6];
    const float* w2r = (const float*)d_in[7];
    float* out = (float*)d_out;

    const int* src = ei;
    const int* dst = ei + EE;

    char* ws = (char*)d_ws;
    auto align = [](size_t v) { return (v + 255) & ~(size_t)255; };
    int*   rowoff = (int*)ws;                 size_t o = align((size_t)(NN + 1) * 4);
    int*   bcur   = (int*)(ws + o);           o += align((size_t)NB * 4);
    int*   bsum   = (int*)(ws + o);           o += align((size_t)NB * 4);
    int*   rec    = (int*)(ws + o);           o += align((size_t)NB * CAP * 4);     // 4.8 MB
    unsigned short* csr = (unsigned short*)(ws + o); o += align((size_t)EE * 2);    // 1.6 MB
    unsigned short* wt1 = (unsigned short*)(ws + o); o += align((size_t)256 * 128 * 2);
    unsigned short* wt2 = (unsigned short*)(ws + o); o += align((size_t)128 * 128 * 2);
    unsigned short* y1  = (unsigned short*)(ws + o); o += align((size_t)(NN + 1) * 128 * 2);
    float*          r1  = (float*)(ws + o);          o += align((size_t)NN * 128 * 4);
    unsigned short* h1  = (unsigned short*)(ws + o); o += align((size_t)NN * 128 * 2);
    unsigned short* y2  = (unsigned short*)(ws + o); o += align((size_t)(NN + 1) * 64 * 2);
    float*          r2  = (float*)(ws + o);          o += align((size_t)NN * 64 * 4);

    // ---- prep (weights + pad rows + bcur=0), then CSR build ----
    prep_all_kernel<<<194, 256, 0, stream>>>(w1l, w1r, w2l, w2r, wt1, wt2,
                                             y1 + (size_t)NN * 128, y2 + (size_t)NN * 64, bcur);
    bin_kernel<<<128, 1024, 0, stream>>>(src, dst, bcur, rec, EE);
    scan2_kernel<<<1, 256, 0, stream>>>(bcur, bsum, NB);
    place_kernel<<<NB, 256, 0, stream>>>(rec, bcur, bsum, rowoff, csr, NN);

    // ---- layer 1: MFMA transform (y1 bf16, r1 fp32) then gather+norm -> h1 bf16 ----
    transform_mfma_kernel<256, false><<<dim3((NN + 63) / 64, 4), 256, 0, stream>>>(
        x, wt1, b1, y1, r1, NN);
    gather128_kernel<true><<<(NN + 3) / 4, 256, 0, stream>>>(y1, r1, rowoff, csr, h1, NN);

    // ---- layer 2: bf16-input transform then gather+norm -> out fp32 ----
    transform_mfma_kernel<128, true><<<dim3((NN + 63) / 64, 2), 256, 0, stream>>>(
        h1, wt2, b2, y2, r2, NN);
    gather64_kernel<<<(NN + 3) / 4, 256, 0, stream>>>(y2, r2, rowoff, csr, out, NN);
}

// Round 11
// 201.226 us; speedup vs baseline: 3.3377x; 1.0212x over previous
//
#include <hip/hip_runtime.h>
#include <math.h>

#define NN 50000
#define EE 800000
#define NB 196     // ceil(NN/256) : coarse buckets (256 nodes each)
#define CAP 6144   // bucket capacity (mean 4081, sigma~64)

typedef __attribute__((ext_vector_type(8))) short bf16x8;
typedef __attribute__((ext_vector_type(16))) float f32x16;
typedef __attribute__((ext_vector_type(4))) unsigned short us4;

__device__ inline unsigned short bf16_rne(float f) {
    union { float f; unsigned u; } a; a.f = f;
    unsigned u = a.u;
    u += 0x7fff + ((u >> 16) & 1);
    return (unsigned short)(u >> 16);
}
__device__ inline float bf16_lo(unsigned v) {
    union { unsigned u; float f; } a; a.u = v << 16;
    return a.f;
}
__device__ inline float bf16_hi(unsigned v) {
    union { unsigned u; float f; } a; a.u = v & 0xffff0000u;
    return a.f;
}

// ---------------- prep: weight bf16-transpose (both layers) + zero pads + zero bcur ----
__global__ void prep_all_kernel(const float* __restrict__ w1l, const float* __restrict__ w1r,
                                const float* __restrict__ w2l, const float* __restrict__ w2r,
                                unsigned short* __restrict__ wt1, unsigned short* __restrict__ wt2,
                                unsigned short* __restrict__ y1pad, unsigned short* __restrict__ y2pad,
                                int* __restrict__ bcur) {
    int idx = blockIdx.x * 256 + threadIdx.x;
    if (idx < 32768) {                 // wt1: 2*128 x 128
        int n = idx >> 7, k = idx & 127;
        float v = (n < 128) ? w1l[(size_t)k * 128 + n] : w1r[(size_t)k * 128 + (n - 128)];
        wt1[idx] = bf16_rne(v);
    } else if (idx < 49152) {          // wt2: 2*64 x 128
        int j = idx - 32768;
        int n = j >> 7, k = j & 127;
        float v = (n < 64) ? w2l[(size_t)k * 64 + n] : w2r[(size_t)k * 64 + (n - 64)];
        wt2[j] = bf16_rne(v);
    } else {
        int j = idx - 49152;
        if (j < 128) y1pad[j] = 0;            // zero row at y1[NN]
        else if (j < 192) y2pad[j - 128] = 0; // zero row at y2[NN]
        else if (j < 192 + NB) bcur[j - 192] = 0;
    }
}

// ---------------- CSR build: bucketed counting sort ----------------
__global__ __launch_bounds__(1024) void bin_kernel(
        const int* __restrict__ src, const int* __restrict__ dst,
        int* __restrict__ gcur, int* __restrict__ rec, int E) {
    __shared__ int hist[NB];
    __shared__ int cur[NB];
    const int t = threadIdx.x;
    const int per = (E + gridDim.x - 1) / gridDim.x;
    const int lo = blockIdx.x * per;
    const int hi = min(lo + per, E);

    for (int i = t; i < NB; i += 1024) hist[i] = 0;
    __syncthreads();
    for (int e = lo + t; e < hi; e += 1024)
        atomicAdd(&hist[dst[e] >> 8], 1);
    __syncthreads();
    for (int i = t; i < NB; i += 1024)
        cur[i] = atomicAdd(&gcur[i], hist[i]);   // block-level reservation
    __syncthreads();
    for (int e = lo + t; e < hi; e += 1024) {
        int d = dst[e], s = src[e];
        int cb = d >> 8;
        int p = atomicAdd(&cur[cb], 1);          // LDS cursor
        if (p < CAP) rec[(size_t)cb * CAP + p] = ((d & 255) << 16) | s;
    }
}

// per-bucket LDS counting sort -> rowoff + contiguous csr segment.
// Bucket-count scan (196 values) inlined per block.
__global__ __launch_bounds__(256) void place_kernel(
        const int* __restrict__ rec, const int* __restrict__ bcur,
        int* __restrict__ rowoff, unsigned short* __restrict__ csr, int n) {
    __shared__ int bscan[256];
    __shared__ int cnt[256];
    __shared__ int cur[256];
    __shared__ unsigned short sorted[CAP];
    const int cb = blockIdx.x, t = threadIdx.x;

    // inclusive scan of all bucket counts -> base for this bucket
    bscan[t] = (t < NB) ? bcur[t] : 0;
    __syncthreads();
    for (int ofs = 1; ofs < 256; ofs <<= 1) {
        int v = bscan[t];
        int a = (t >= ofs) ? bscan[t - ofs] : 0;
        __syncthreads();
        bscan[t] = v + a;
        __syncthreads();
    }
    const int base = (cb == 0) ? 0 : bscan[cb - 1];

    int m = bcur[cb]; if (m > CAP) m = CAP;
    const int* r = rec + (size_t)cb * CAP;

    cnt[t] = 0;
    __syncthreads();
    for (int i = t; i < m; i += 256) atomicAdd(&cnt[r[i] >> 16], 1);
    __syncthreads();
    int orig = cnt[t];
    for (int ofs = 1; ofs < 256; ofs <<= 1) {
        int v = cnt[t];
        int a = (t >= ofs) ? cnt[t - ofs] : 0;
        __syncthreads();
        cnt[t] = v + a;
        __syncthreads();
    }
    int excl = cnt[t] - orig;
    int node = cb * 256 + t;
    if (node < n) rowoff[node] = base + excl;
    if (node == n - 1) rowoff[n] = base + cnt[t];
    cur[t] = excl;
    __syncthreads();
    for (int i = t; i < m; i += 256) {
        int rr = r[i];
        int pos = atomicAdd(&cur[rr >> 16], 1);
        sorted[pos] = (unsigned short)(rr & 0xffff);
    }
    __syncthreads();
    for (int i = t; i < m; i += 256) csr[base + i] = sorted[i];
}

// ---------------- MFMA transform ----------------
// ybuf bf16 (cols<HALF), rbuf bf16 (+bias).
template <int CO, bool BF16IN>
__global__ __launch_bounds__(256) void transform_mfma_kernel(
        const void* __restrict__ xin, const unsigned short* __restrict__ wt,
        const float* __restrict__ bias, unsigned short* __restrict__ ybuf,
        unsigned short* __restrict__ rbuf, int n) {
    constexpr int HALF = CO / 2;
    constexpr int LDW = 136;
    __shared__ unsigned short Xs[64][LDW];
    __shared__ unsigned short Ws[64][LDW];

    const int t = threadIdx.x;
    const int node0 = blockIdx.x * 64;
    const int gy = blockIdx.y;

    if (BF16IN) {
        const unsigned short* xb = (const unsigned short*)xin;
        for (int e = t; e < 64 * 16; e += 256) {
            int nd = e >> 4, c8 = e & 15;
            int node = node0 + nd;
            int4 v = (node < n) ? ((const int4*)(xb + (size_t)node * 128))[c8]
                                : make_int4(0, 0, 0, 0);
            *(int4*)&Xs[nd][c8 * 8] = v;
        }
    } else {
        const float* xf = (const float*)xin;
        for (int e = t; e < 64 * 32; e += 256) {
            int nd = e >> 5, c4 = e & 31;
            int node = node0 + nd;
            float4 v = (node < n) ? ((const float4*)xf)[(size_t)node * 32 + c4]
                                  : make_float4(0.f, 0.f, 0.f, 0.f);
            us4 p;
            p.x = bf16_rne(v.x); p.y = bf16_rne(v.y); p.z = bf16_rne(v.z); p.w = bf16_rne(v.w);
            *(us4*)&Xs[nd][c4 * 4] = p;
        }
    }
    for (int e = t; e < 64 * 16; e += 256) {
        int nd = e >> 4, c8 = e & 15;
        int4 v = ((const int4*)(wt + ((size_t)(gy * 64 + nd)) * 128))[c8];
        *(int4*)&Ws[nd][c8 * 8] = v;
    }
    __syncthreads();

    const int lane = t & 63, wave = t >> 6;
    const int wm = (wave & 1) * 32, wn = (wave >> 1) * 32;
    const int ml = wm + (lane & 31);
    const int nl = wn + (lane & 31);
    const int koff = (lane >> 5) * 8;

    f32x16 acc;
#pragma unroll
    for (int r = 0; r < 16; r++) acc[r] = 0.f;

#pragma unroll
    for (int kk = 0; kk < 8; kk++) {
        bf16x8 a = *(const bf16x8*)&Xs[ml][kk * 16 + koff];
        bf16x8 b = *(const bf16x8*)&Ws[nl][kk * 16 + koff];
        acc = __builtin_amdgcn_mfma_f32_32x32x16_bf16(a, b, acc, 0, 0, 0);
    }

    const int col = gy * 64 + wn + (lane & 31);
    if (col < HALF) {
#pragma unroll
        for (int r = 0; r < 16; r++) {
            int row = (r & 3) + 8 * (r >> 2) + 4 * (lane >> 5);
            int node = node0 + wm + row;
            if (node < n) ybuf[(size_t)node * HALF + col] = bf16_rne(acc[r]);
        }
    } else {
        const float bj = bias[col - HALF];
#pragma unroll
        for (int r = 0; r < 16; r++) {
            int row = (r & 3) + 8 * (r >> 2) + 4 * (lane >> 5);
            int node = node0 + wm + row;
            if (node < n) rbuf[(size_t)node * HALF + (col - HALF)] = bf16_rne(acc[r] + bj);
        }
    }
}

// ---------------- gather + mean + add-root + L2norm, D=128, bf16 out ----------------
// 16-lane groups: each group loads one 256B y-row as dwordx4 -> 4 rows/instr.
__global__ __launch_bounds__(256) void gather128_kernel(
        const unsigned short* __restrict__ y, const unsigned short* __restrict__ rrb,
        const int* __restrict__ rowoff, const unsigned short* __restrict__ csr,
        unsigned short* __restrict__ out, int n) {
    const int wave = threadIdx.x >> 6;
    const int lane = threadIdx.x & 63;
    const int node = blockIdx.x * 4 + wave;
    if (node >= n) return;
    const int g = lane >> 4;        // group 0..3
    const int q = lane & 15;        // col chunk: cols q*8..q*8+7

    const int off = rowoff[node];
    const int end = rowoff[node + 1];
    const int deg = end - off;

    float acc[8];
#pragma unroll
    for (int j = 0; j < 8; j++) acc[j] = 0.f;

    for (int k0 = 0; k0 < deg; k0 += 8) {
        int kk0 = off + k0 + g;
        int kk1 = off + k0 + 4 + g;
        int i0 = (kk0 < end) ? (int)csr[kk0] : n;   // n = zero row
        int i1 = (kk1 < end) ? (int)csr[kk1] : n;
        uint4 v0 = *(const uint4*)(y + (size_t)i0 * 128 + q * 8);
        uint4 v1 = *(const uint4*)(y + (size_t)i1 * 128 + q * 8);
        const unsigned* u0 = (const unsigned*)&v0;
        const unsigned* u1 = (const unsigned*)&v1;
#pragma unroll
        for (int i = 0; i < 4; i++) {
            acc[2 * i]     += bf16_lo(u0[i]) + bf16_lo(u1[i]);
            acc[2 * i + 1] += bf16_hi(u0[i]) + bf16_hi(u1[i]);
        }
    }
    // combine the 4 groups (each holds partial sums for the same cols)
#pragma unroll
    for (int j = 0; j < 8; j++) {
        acc[j] += __shfl_xor(acc[j], 16, 64);
        acc[j] += __shfl_xor(acc[j], 32, 64);
    }
    const float im = 1.0f / fmaxf((float)deg, 1.0f);
    uint4 rv = *(const uint4*)(rrb + (size_t)node * 128 + q * 8);
    const unsigned* ru = (const unsigned*)&rv;
    float v[8];
    float ss = 0.f;
#pragma unroll
    for (int i = 0; i < 4; i++) {
        v[2 * i]     = acc[2 * i] * im     + bf16_lo(ru[i]);
        v[2 * i + 1] = acc[2 * i + 1] * im + bf16_hi(ru[i]);
    }
#pragma unroll
    for (int j = 0; j < 8; j++) ss += v[j] * v[j];
#pragma unroll
    for (int m = 8; m >= 1; m >>= 1) ss += __shfl_xor(ss, m, 64);
    const float rn = 1.0f / fmaxf(sqrtf(ss), 1e-12f);
    if (g == 0) {
        uint4 pk;
        unsigned* pu = (unsigned*)&pk;
#pragma unroll
        for (int i = 0; i < 4; i++)
            pu[i] = (unsigned)bf16_rne(v[2 * i] * rn) |
                    ((unsigned)bf16_rne(v[2 * i + 1] * rn) << 16);
        *(uint4*)(out + (size_t)node * 128 + q * 8) = pk;
    }
}

// ---------------- gather + mean + add-root + L2norm, D=64, fp32 out ----------------
// 8-lane groups: each group loads one 128B y-row as dwordx4 -> 8 rows/instr.
__global__ __launch_bounds__(256) void gather64_kernel(
        const unsigned short* __restrict__ y, const unsigned short* __restrict__ rrb,
        const int* __restrict__ rowoff, const unsigned short* __restrict__ csr,
        float* __restrict__ out, int n) {
    const int wave = threadIdx.x >> 6;
    const int lane = threadIdx.x & 63;
    const int node = blockIdx.x * 4 + wave;
    if (node >= n) return;
    const int g = lane >> 3;        // group 0..7
    const int q = lane & 7;         // col chunk: cols q*8..q*8+7

    const int off = rowoff[node];
    const int end = rowoff[node + 1];
    const int deg = end - off;

    float acc[8];
#pragma unroll
    for (int j = 0; j < 8; j++) acc[j] = 0.f;

    for (int k0 = 0; k0 < deg; k0 += 16) {
        int kk0 = off + k0 + g;
        int kk1 = off + k0 + 8 + g;
        int i0 = (kk0 < end) ? (int)csr[kk0] : n;
        int i1 = (kk1 < end) ? (int)csr[kk1] : n;
        uint4 v0 = *(const uint4*)(y + (size_t)i0 * 64 + q * 8);
        uint4 v1 = *(const uint4*)(y + (size_t)i1 * 64 + q * 8);
        const unsigned* u0 = (const unsigned*)&v0;
        const unsigned* u1 = (const unsigned*)&v1;
#pragma unroll
        for (int i = 0; i < 4; i++) {
            acc[2 * i]     += bf16_lo(u0[i]) + bf16_lo(u1[i]);
            acc[2 * i + 1] += bf16_hi(u0[i]) + bf16_hi(u1[i]);
        }
    }
    // combine the 8 groups
#pragma unroll
    for (int j = 0; j < 8; j++) {
        acc[j] += __shfl_xor(acc[j], 8, 64);
        acc[j] += __shfl_xor(acc[j], 16, 64);
        acc[j] += __shfl_xor(acc[j], 32, 64);
    }
    const float im = 1.0f / fmaxf((float)deg, 1.0f);
    uint4 rv = *(const uint4*)(rrb + (size_t)node * 64 + q * 8);
    const unsigned* ru = (const unsigned*)&rv;
    float v[8];
    float ss = 0.f;
#pragma unroll
    for (int i = 0; i < 4; i++) {
        v[2 * i]     = acc[2 * i] * im     + bf16_lo(ru[i]);
        v[2 * i + 1] = acc[2 * i + 1] * im + bf16_hi(ru[i]);
    }
#pragma unroll
    for (int j = 0; j < 8; j++) ss += v[j] * v[j];
#pragma unroll
    for (int m = 4; m >= 1; m >>= 1) ss += __shfl_xor(ss, m, 64);
    const float rn = 1.0f / fmaxf(sqrtf(ss), 1e-12f);
    if (g == 0) {
        float4 o0 = make_float4(v[0] * rn, v[1] * rn, v[2] * rn, v[3] * rn);
        float4 o1 = make_float4(v[4] * rn, v[5] * rn, v[6] * rn, v[7] * rn);
        *(float4*)(out + (size_t)node * 64 + q * 8) = o0;
        *(float4*)(out + (size_t)node * 64 + q * 8 + 4) = o1;
    }
}

extern "C" void kernel_launch(void* const* d_in, const int* in_sizes, int n_in,
                              void* d_out, int out_size, void* d_ws, size_t ws_size,
                              hipStream_t stream) {
    const float* x   = (const float*)d_in[0];
    const int*   ei  = (const int*)d_in[1];   // [2, E] int32
    const float* w1l = (const float*)d_in[2];
    const float* b1  = (const float*)d_in[3];
    const float* w1r = (const float*)d_in[4];
    const float* w2l = (const float*)d_in[5];
    const float* b2  = (const float*)d_in[6];
    const float* w2r = (const float*)d_in[7];
    float* out = (float*)d_out;

    const int* src = ei;
    const int* dst = ei + EE;

    char* ws = (char*)d_ws;
    auto align = [](size_t v) { return (v + 255) & ~(size_t)255; };
    int*   rowoff = (int*)ws;                 size_t o = align((size_t)(NN + 1) * 4);
    int*   bcur   = (int*)(ws + o);           o += align((size_t)NB * 4);
    int*   rec    = (int*)(ws + o);           o += align((size_t)NB * CAP * 4);     // 4.8 MB
    unsigned short* csr = (unsigned short*)(ws + o); o += align((size_t)EE * 2);    // 1.6 MB
    unsigned short* wt1 = (unsigned short*)(ws + o); o += align((size_t)256 * 128 * 2);
    unsigned short* wt2 = (unsigned short*)(ws + o); o += align((size_t)128 * 128 * 2);
    unsigned short* y1  = (unsigned short*)(ws + o); o += align((size_t)(NN + 1) * 128 * 2);
    unsigned short* r1  = (unsigned short*)(ws + o); o += align((size_t)NN * 128 * 2);
    unsigned short* h1  = (unsigned short*)(ws + o); o += align((size_t)NN * 128 * 2);
    unsigned short* y2  = (unsigned short*)(ws + o); o += align((size_t)(NN + 1) * 64 * 2);
    unsigned short* r2  = (unsigned short*)(ws + o); o += align((size_t)NN * 64 * 2);

    // ---- prep (weights + pad rows + bcur=0), then CSR build ----
    prep_all_kernel<<<194, 256, 0, stream>>>(w1l, w1r, w2l, w2r, wt1, wt2,
                                             y1 + (size_t)NN * 128, y2 + (size_t)NN * 64, bcur);
    bin_kernel<<<256, 1024, 0, stream>>>(src, dst, bcur, rec, EE);
    place_kernel<<<NB, 256, 0, stream>>>(rec, bcur, rowoff, csr, NN);

    // ---- layer 1: MFMA transform (y1, r1 bf16) then gather+norm -> h1 bf16 ----
    transform_mfma_kernel<256, false><<<dim3((NN + 63) / 64, 4), 256, 0, stream>>>(
        x, wt1, b1, y1, r1, NN);
    gather128_kernel<<<(NN + 3) / 4, 256, 0, stream>>>(y1, r1, rowoff, csr, h1, NN);

    // ---- layer 2: bf16-input transform then gather+norm -> out fp32 ----
    transform_mfma_kernel<128, true><<<dim3((NN + 63) / 64, 2), 256, 0, stream>>>(
        h1, wt2, b2, y2, r2, NN);
    gather64_kernel<<<(NN + 3) / 4, 256, 0, stream>>>(y2, r2, rowoff, csr, out, NN);
}

// Round 12
// 189.593 us; speedup vs baseline: 3.5425x; 1.0614x over previous
//
#include <hip/hip_runtime.h>
#include <math.h>

#define NN 50000
#define EE 800000
#define NB 196     // ceil(NN/256) : coarse buckets (256 nodes each)
#define CAP 6144   // bucket capacity (mean 4081, sigma~64)

typedef __attribute__((ext_vector_type(8))) short bf16x8;
typedef __attribute__((ext_vector_type(16))) float f32x16;
typedef __attribute__((ext_vector_type(4))) unsigned short us4;

__device__ inline unsigned short bf16_rne(float f) {
    union { float f; unsigned u; } a; a.f = f;
    unsigned u = a.u;
    u += 0x7fff + ((u >> 16) & 1);
    return (unsigned short)(u >> 16);
}
__device__ inline float bf16_lo(unsigned v) {
    union { unsigned u; float f; } a; a.u = v << 16;
    return a.f;
}
__device__ inline float bf16_hi(unsigned v) {
    union { unsigned u; float f; } a; a.u = v & 0xffff0000u;
    return a.f;
}

// ---------------- prep: weight bf16-transpose (both layers) + zero pads + zero bcur ----
__global__ void prep_all_kernel(const float* __restrict__ w1l, const float* __restrict__ w1r,
                                const float* __restrict__ w2l, const float* __restrict__ w2r,
                                unsigned short* __restrict__ wt1, unsigned short* __restrict__ wt2,
                                unsigned short* __restrict__ y1pad, unsigned short* __restrict__ y2pad,
                                int* __restrict__ bcur) {
    int idx = blockIdx.x * 256 + threadIdx.x;
    if (idx < 32768) {                 // wt1: 2*128 x 128
        int n = idx >> 7, k = idx & 127;
        float v = (n < 128) ? w1l[(size_t)k * 128 + n] : w1r[(size_t)k * 128 + (n - 128)];
        wt1[idx] = bf16_rne(v);
    } else if (idx < 49152) {          // wt2: 2*64 x 128
        int j = idx - 32768;
        int n = j >> 7, k = j & 127;
        float v = (n < 64) ? w2l[(size_t)k * 64 + n] : w2r[(size_t)k * 64 + (n - 64)];
        wt2[j] = bf16_rne(v);
    } else {
        int j = idx - 49152;
        if (j < 128) y1pad[j] = 0;            // zero row at y1[NN]
        else if (j < 192) y2pad[j - 128] = 0; // zero row at y2[NN]
        else if (j < 192 + NB) bcur[j - 192] = 0;
    }
}

// ---------------- CSR build: bucketed counting sort ----------------
__global__ __launch_bounds__(1024) void bin_kernel(
        const int* __restrict__ src, const int* __restrict__ dst,
        int* __restrict__ gcur, int* __restrict__ rec, int E) {
    __shared__ int hist[NB];
    __shared__ int cur[NB];
    const int t = threadIdx.x;
    const int per = (E + gridDim.x - 1) / gridDim.x;
    const int lo = blockIdx.x * per;
    const int hi = min(lo + per, E);

    for (int i = t; i < NB; i += 1024) hist[i] = 0;
    __syncthreads();
    for (int e = lo + t; e < hi; e += 1024)
        atomicAdd(&hist[dst[e] >> 8], 1);
    __syncthreads();
    for (int i = t; i < NB; i += 1024)
        cur[i] = atomicAdd(&gcur[i], hist[i]);   // block-level reservation
    __syncthreads();
    for (int e = lo + t; e < hi; e += 1024) {
        int d = dst[e], s = src[e];
        int cb = d >> 8;
        int p = atomicAdd(&cur[cb], 1);          // LDS cursor
        if (p < CAP) rec[(size_t)cb * CAP + p] = ((d & 255) << 16) | s;
    }
}

// per-bucket LDS counting sort -> rowoff + contiguous csr segment.
__global__ __launch_bounds__(256) void place_kernel(
        const int* __restrict__ rec, const int* __restrict__ bcur,
        int* __restrict__ rowoff, unsigned short* __restrict__ csr, int n) {
    __shared__ int bscan[256];
    __shared__ int cnt[256];
    __shared__ int cur[256];
    __shared__ unsigned short sorted[CAP];
    const int cb = blockIdx.x, t = threadIdx.x;

    bscan[t] = (t < NB) ? bcur[t] : 0;
    __syncthreads();
    for (int ofs = 1; ofs < 256; ofs <<= 1) {
        int v = bscan[t];
        int a = (t >= ofs) ? bscan[t - ofs] : 0;
        __syncthreads();
        bscan[t] = v + a;
        __syncthreads();
    }
    const int base = (cb == 0) ? 0 : bscan[cb - 1];

    int m = bcur[cb]; if (m > CAP) m = CAP;
    const int* r = rec + (size_t)cb * CAP;

    cnt[t] = 0;
    __syncthreads();
    for (int i = t; i < m; i += 256) atomicAdd(&cnt[r[i] >> 16], 1);
    __syncthreads();
    int orig = cnt[t];
    for (int ofs = 1; ofs < 256; ofs <<= 1) {
        int v = cnt[t];
        int a = (t >= ofs) ? cnt[t - ofs] : 0;
        __syncthreads();
        cnt[t] = v + a;
        __syncthreads();
    }
    int excl = cnt[t] - orig;
    int node = cb * 256 + t;
    if (node < n) rowoff[node] = base + excl;
    if (node == n - 1) rowoff[n] = base + cnt[t];
    cur[t] = excl;
    __syncthreads();
    for (int i = t; i < m; i += 256) {
        int rr = r[i];
        int pos = atomicAdd(&cur[rr >> 16], 1);
        sorted[pos] = (unsigned short)(rr & 0xffff);
    }
    __syncthreads();
    for (int i = t; i < m; i += 256) csr[base + i] = sorted[i];
}

// ---------------- MFMA transform ----------------
template <int CO, bool BF16IN>
__global__ __launch_bounds__(256) void transform_mfma_kernel(
        const void* __restrict__ xin, const unsigned short* __restrict__ wt,
        const float* __restrict__ bias, unsigned short* __restrict__ ybuf,
        unsigned short* __restrict__ rbuf, int n) {
    constexpr int HALF = CO / 2;
    constexpr int LDW = 136;
    __shared__ unsigned short Xs[64][LDW];
    __shared__ unsigned short Ws[64][LDW];

    const int t = threadIdx.x;
    const int node0 = blockIdx.x * 64;
    const int gy = blockIdx.y;

    if (BF16IN) {
        const unsigned short* xb = (const unsigned short*)xin;
        for (int e = t; e < 64 * 16; e += 256) {
            int nd = e >> 4, c8 = e & 15;
            int node = node0 + nd;
            int4 v = (node < n) ? ((const int4*)(xb + (size_t)node * 128))[c8]
                                : make_int4(0, 0, 0, 0);
            *(int4*)&Xs[nd][c8 * 8] = v;
        }
    } else {
        const float* xf = (const float*)xin;
        for (int e = t; e < 64 * 32; e += 256) {
            int nd = e >> 5, c4 = e & 31;
            int node = node0 + nd;
            float4 v = (node < n) ? ((const float4*)xf)[(size_t)node * 32 + c4]
                                  : make_float4(0.f, 0.f, 0.f, 0.f);
            us4 p;
            p.x = bf16_rne(v.x); p.y = bf16_rne(v.y); p.z = bf16_rne(v.z); p.w = bf16_rne(v.w);
            *(us4*)&Xs[nd][c4 * 4] = p;
        }
    }
    for (int e = t; e < 64 * 16; e += 256) {
        int nd = e >> 4, c8 = e & 15;
        int4 v = ((const int4*)(wt + ((size_t)(gy * 64 + nd)) * 128))[c8];
        *(int4*)&Ws[nd][c8 * 8] = v;
    }
    __syncthreads();

    const int lane = t & 63, wave = t >> 6;
    const int wm = (wave & 1) * 32, wn = (wave >> 1) * 32;
    const int ml = wm + (lane & 31);
    const int nl = wn + (lane & 31);
    const int koff = (lane >> 5) * 8;

    f32x16 acc;
#pragma unroll
    for (int r = 0; r < 16; r++) acc[r] = 0.f;

#pragma unroll
    for (int kk = 0; kk < 8; kk++) {
        bf16x8 a = *(const bf16x8*)&Xs[ml][kk * 16 + koff];
        bf16x8 b = *(const bf16x8*)&Ws[nl][kk * 16 + koff];
        acc = __builtin_amdgcn_mfma_f32_32x32x16_bf16(a, b, acc, 0, 0, 0);
    }

    const int col = gy * 64 + wn + (lane & 31);
    if (col < HALF) {
#pragma unroll
        for (int r = 0; r < 16; r++) {
            int row = (r & 3) + 8 * (r >> 2) + 4 * (lane >> 5);
            int node = node0 + wm + row;
            if (node < n) ybuf[(size_t)node * HALF + col] = bf16_rne(acc[r]);
        }
    } else {
        const float bj = bias[col - HALF];
#pragma unroll
        for (int r = 0; r < 16; r++) {
            int row = (r & 3) + 8 * (r >> 2) + 4 * (lane >> 5);
            int node = node0 + wm + row;
            if (node < n) rbuf[(size_t)node * HALF + (col - HALF)] = bf16_rne(acc[r] + bj);
        }
    }
}

// ---------------- gather + mean + add-root + L2norm, D=128, bf16 out ----------------
// One 16-lane group per node: each row load = 16 lanes x 16B = 256B (whole row),
// 8 rows unrolled in flight, 4 independent node streams per wave.
__global__ __launch_bounds__(256) void gather128_kernel(
        const unsigned short* __restrict__ y, const unsigned short* __restrict__ rrb,
        const int* __restrict__ rowoff, const unsigned short* __restrict__ csr,
        unsigned short* __restrict__ out, int n) {
    const int gi = threadIdx.x >> 4;     // group 0..15
    const int q  = threadIdx.x & 15;     // col chunk: cols q*8..q*8+7
    const int node = blockIdx.x * 16 + gi;
    if (node >= n) return;

    const int off = rowoff[node];
    const int end = rowoff[node + 1];
    const int deg = end - off;

    float acc[8];
#pragma unroll
    for (int j = 0; j < 8; j++) acc[j] = 0.f;

    for (int k0 = 0; k0 < deg; k0 += 8) {
        int idx[8];
#pragma unroll
        for (int j = 0; j < 8; j++) {
            int kk = off + k0 + j;
            idx[j] = (kk < end) ? (int)csr[kk] : n;   // n = zero row
        }
        uint4 v[8];
#pragma unroll
        for (int j = 0; j < 8; j++)
            v[j] = *(const uint4*)(y + (size_t)idx[j] * 128 + q * 8);
#pragma unroll
        for (int j = 0; j < 8; j++) {
            const unsigned* u = (const unsigned*)&v[j];
#pragma unroll
            for (int i = 0; i < 4; i++) {
                acc[2 * i]     += bf16_lo(u[i]);
                acc[2 * i + 1] += bf16_hi(u[i]);
            }
        }
    }
    const float im = 1.0f / fmaxf((float)deg, 1.0f);
    uint4 rv = *(const uint4*)(rrb + (size_t)node * 128 + q * 8);
    const unsigned* ru = (const unsigned*)&rv;
    float v[8];
    float ss = 0.f;
#pragma unroll
    for (int i = 0; i < 4; i++) {
        v[2 * i]     = acc[2 * i] * im     + bf16_lo(ru[i]);
        v[2 * i + 1] = acc[2 * i + 1] * im + bf16_hi(ru[i]);
    }
#pragma unroll
    for (int j = 0; j < 8; j++) ss += v[j] * v[j];
#pragma unroll
    for (int m = 8; m >= 1; m >>= 1) ss += __shfl_xor(ss, m, 64);  // within 16-lane group
    const float rn = 1.0f / fmaxf(sqrtf(ss), 1e-12f);
    uint4 pk;
    unsigned* pu = (unsigned*)&pk;
#pragma unroll
    for (int i = 0; i < 4; i++)
        pu[i] = (unsigned)bf16_rne(v[2 * i] * rn) |
                ((unsigned)bf16_rne(v[2 * i + 1] * rn) << 16);
    *(uint4*)(out + (size_t)node * 128 + q * 8) = pk;
}

// ---------------- gather + mean + add-root + L2norm, D=64, fp32 out ----------------
// One 8-lane group per node: row load = 8 lanes x 16B = 128B, 8 rows in flight,
// 8 independent node streams per wave.
__global__ __launch_bounds__(256) void gather64_kernel(
        const unsigned short* __restrict__ y, const unsigned short* __restrict__ rrb,
        const int* __restrict__ rowoff, const unsigned short* __restrict__ csr,
        float* __restrict__ out, int n) {
    const int gi = threadIdx.x >> 3;     // group 0..31
    const int q  = threadIdx.x & 7;      // col chunk: cols q*8..q*8+7
    const int node = blockIdx.x * 32 + gi;
    if (node >= n) return;

    const int off = rowoff[node];
    const int end = rowoff[node + 1];
    const int deg = end - off;

    float acc[8];
#pragma unroll
    for (int j = 0; j < 8; j++) acc[j] = 0.f;

    for (int k0 = 0; k0 < deg; k0 += 8) {
        int idx[8];
#pragma unroll
        for (int j = 0; j < 8; j++) {
            int kk = off + k0 + j;
            idx[j] = (kk < end) ? (int)csr[kk] : n;
        }
        uint4 v[8];
#pragma unroll
        for (int j = 0; j < 8; j++)
            v[j] = *(const uint4*)(y + (size_t)idx[j] * 64 + q * 8);
#pragma unroll
        for (int j = 0; j < 8; j++) {
            const unsigned* u = (const unsigned*)&v[j];
#pragma unroll
            for (int i = 0; i < 4; i++) {
                acc[2 * i]     += bf16_lo(u[i]);
                acc[2 * i + 1] += bf16_hi(u[i]);
            }
        }
    }
    const float im = 1.0f / fmaxf((float)deg, 1.0f);
    uint4 rv = *(const uint4*)(rrb + (size_t)node * 64 + q * 8);
    const unsigned* ru = (const unsigned*)&rv;
    float v[8];
    float ss = 0.f;
#pragma unroll
    for (int i = 0; i < 4; i++) {
        v[2 * i]     = acc[2 * i] * im     + bf16_lo(ru[i]);
        v[2 * i + 1] = acc[2 * i + 1] * im + bf16_hi(ru[i]);
    }
#pragma unroll
    for (int j = 0; j < 8; j++) ss += v[j] * v[j];
#pragma unroll
    for (int m = 4; m >= 1; m >>= 1) ss += __shfl_xor(ss, m, 64);  // within 8-lane group
    const float rn = 1.0f / fmaxf(sqrtf(ss), 1e-12f);
    float4 o0 = make_float4(v[0] * rn, v[1] * rn, v[2] * rn, v[3] * rn);
    float4 o1 = make_float4(v[4] * rn, v[5] * rn, v[6] * rn, v[7] * rn);
    *(float4*)(out + (size_t)node * 64 + q * 8) = o0;
    *(float4*)(out + (size_t)node * 64 + q * 8 + 4) = o1;
}

extern "C" void kernel_launch(void* const* d_in, const int* in_sizes, int n_in,
                              void* d_out, int out_size, void* d_ws, size_t ws_size,
                              hipStream_t stream) {
    const float* x   = (const float*)d_in[0];
    const int*   ei  = (const int*)d_in[1];   // [2, E] int32
    const float* w1l = (const float*)d_in[2];
    const float* b1  = (const float*)d_in[3];
    const float* w1r = (const float*)d_in[4];
    const float* w2l = (const float*)d_in[5];
    const float* b2  = (const float*)d_in[6];
    const float* w2r = (const float*)d_in[7];
    float* out = (float*)d_out;

    const int* src = ei;
    const int* dst = ei + EE;

    char* ws = (char*)d_ws;
    auto align = [](size_t v) { return (v + 255) & ~(size_t)255; };
    int*   rowoff = (int*)ws;                 size_t o = align((size_t)(NN + 1) * 4);
    int*   bcur   = (int*)(ws + o);           o += align((size_t)NB * 4);
    int*   rec    = (int*)(ws + o);           o += align((size_t)NB * CAP * 4);     // 4.8 MB
    unsigned short* csr = (unsigned short*)(ws + o); o += align((size_t)EE * 2);    // 1.6 MB
    unsigned short* wt1 = (unsigned short*)(ws + o); o += align((size_t)256 * 128 * 2);
    unsigned short* wt2 = (unsigned short*)(ws + o); o += align((size_t)128 * 128 * 2);
    unsigned short* y1  = (unsigned short*)(ws + o); o += align((size_t)(NN + 1) * 128 * 2);
    unsigned short* r1  = (unsigned short*)(ws + o); o += align((size_t)NN * 128 * 2);
    unsigned short* h1  = (unsigned short*)(ws + o); o += align((size_t)NN * 128 * 2);
    unsigned short* y2  = (unsigned short*)(ws + o); o += align((size_t)(NN + 1) * 64 * 2);
    unsigned short* r2  = (unsigned short*)(ws + o); o += align((size_t)NN * 64 * 2);

    // ---- prep (weights + pad rows + bcur=0), then CSR build ----
    prep_all_kernel<<<194, 256, 0, stream>>>(w1l, w1r, w2l, w2r, wt1, wt2,
                                             y1 + (size_t)NN * 128, y2 + (size_t)NN * 64, bcur);
    bin_kernel<<<256, 1024, 0, stream>>>(src, dst, bcur, rec, EE);
    place_kernel<<<NB, 256, 0, stream>>>(rec, bcur, rowoff, csr, NN);

    // ---- layer 1: MFMA transform (y1, r1 bf16) then gather+norm -> h1 bf16 ----
    transform_mfma_kernel<256, false><<<dim3((NN + 63) / 64, 4), 256, 0, stream>>>(
        x, wt1, b1, y1, r1, NN);
    gather128_kernel<<<(NN + 15) / 16, 256, 0, stream>>>(y1, r1, rowoff, csr, h1, NN);

    // ---- layer 2: bf16-input transform then gather+norm -> out fp32 ----
    transform_mfma_kernel<128, true><<<dim3((NN + 63) / 64, 2), 256, 0, stream>>>(
        h1, wt2, b2, y2, r2, NN);
    gather64_kernel<<<(NN + 31) / 32, 256, 0, stream>>>(y2, r2, rowoff, csr, out, NN);
}

// Round 13
// 187.983 us; speedup vs baseline: 3.5728x; 1.0086x over previous
//
#include <hip/hip_runtime.h>
#include <math.h>

#define NN 50000
#define EE 800000
#define NB 196     // ceil(NN/256) : coarse buckets (256 nodes each)
#define CAP 6144   // bucket capacity (mean 4081, sigma~64)
#define TB1 3128   // transform1 blocks in fused kernel (782 node-tiles x 4 col-tiles)
#define NBIN 512   // bin blocks in fused kernel

typedef __attribute__((ext_vector_type(8))) short bf16x8;
typedef __attribute__((ext_vector_type(16))) float f32x16;
typedef __attribute__((ext_vector_type(4))) float f32x4;
typedef __attribute__((ext_vector_type(4))) unsigned short us4;

__device__ inline unsigned short bf16_rne(float f) {
    union { float f; unsigned u; } a; a.f = f;
    unsigned u = a.u;
    u += 0x7fff + ((u >> 16) & 1);
    return (unsigned short)(u >> 16);
}
__device__ inline float bf16_lo(unsigned v) {
    union { unsigned u; float f; } a; a.u = v << 16;
    return a.f;
}
__device__ inline float bf16_hi(unsigned v) {
    union { unsigned u; float f; } a; a.u = v & 0xffff0000u;
    return a.f;
}

// ---------------- prep: weight bf16-transpose (both layers) + zero pads + zero bcur ----
__global__ void prep_all_kernel(const float* __restrict__ w1l, const float* __restrict__ w1r,
                                const float* __restrict__ w2l, const float* __restrict__ w2r,
                                unsigned short* __restrict__ wt1, unsigned short* __restrict__ wt2,
                                unsigned short* __restrict__ y1pad, unsigned short* __restrict__ y2pad,
                                int* __restrict__ bcur) {
    int idx = blockIdx.x * 256 + threadIdx.x;
    if (idx < 32768) {                 // wt1: 2*128 x 128
        int n = idx >> 7, k = idx & 127;
        float v = (n < 128) ? w1l[(size_t)k * 128 + n] : w1r[(size_t)k * 128 + (n - 128)];
        wt1[idx] = bf16_rne(v);
    } else if (idx < 49152) {          // wt2: 2*64 x 128
        int j = idx - 32768;
        int n = j >> 7, k = j & 127;
        float v = (n < 64) ? w2l[(size_t)k * 64 + n] : w2r[(size_t)k * 64 + (n - 64)];
        wt2[j] = bf16_rne(v);
    } else {
        int j = idx - 49152;
        if (j < 128) y1pad[j] = 0;            // zero row at y1[NN]
        else if (j < 192) y2pad[j - 128] = 0; // zero row at y2[NN]
        else if (j < 192 + NB) bcur[j - 192] = 0;
    }
}

// ---------------- fused: transform1 (blocks 0..TB1-1) + bin (blocks TB1..TB1+NBIN-1) ----
__global__ __launch_bounds__(256) void fused_t1_bin_kernel(
        const float* __restrict__ x, const unsigned short* __restrict__ wt,
        const float* __restrict__ bias, unsigned short* __restrict__ ybuf,
        unsigned short* __restrict__ rbuf, int n,
        const int* __restrict__ src, const int* __restrict__ dst,
        int* __restrict__ gcur, int* __restrict__ rec, int E) {
    __shared__ unsigned short Xs[64][136];
    __shared__ unsigned short Ws[64][136];
    __shared__ int hist[NB];
    __shared__ int cur[NB];
    const int t = threadIdx.x;

    if (blockIdx.x >= TB1) {
        // ---------- bin ----------
        const int bb = blockIdx.x - TB1;
        const int per = (E + NBIN - 1) / NBIN;
        const int lo = bb * per;
        const int hi = min(lo + per, E);
        for (int i = t; i < NB; i += 256) hist[i] = 0;
        __syncthreads();
        for (int e = lo + t; e < hi; e += 256)
            atomicAdd(&hist[dst[e] >> 8], 1);
        __syncthreads();
        for (int i = t; i < NB; i += 256)
            cur[i] = atomicAdd(&gcur[i], hist[i]);   // block-level reservation
        __syncthreads();
        for (int e = lo + t; e < hi; e += 256) {
            int d = dst[e], s = src[e];
            int cb = d >> 8;
            int p = atomicAdd(&cur[cb], 1);          // LDS cursor
            if (p < CAP) rec[(size_t)cb * CAP + p] = ((d & 255) << 16) | s;
        }
        return;
    }

    // ---------- transform1: 128->256, fp32 input ----------
    constexpr int HALF = 128;
    const int node0 = (blockIdx.x >> 2) * 64;
    const int gy = blockIdx.x & 3;

    for (int e = t; e < 64 * 32; e += 256) {
        int nd = e >> 5, c4 = e & 31;
        int node = node0 + nd;
        float4 v = (node < n) ? ((const float4*)x)[(size_t)node * 32 + c4]
                              : make_float4(0.f, 0.f, 0.f, 0.f);
        us4 p;
        p.x = bf16_rne(v.x); p.y = bf16_rne(v.y); p.z = bf16_rne(v.z); p.w = bf16_rne(v.w);
        *(us4*)&Xs[nd][c4 * 4] = p;
    }
    for (int e = t; e < 64 * 16; e += 256) {
        int nd = e >> 4, c8 = e & 15;
        int4 v = ((const int4*)(wt + ((size_t)(gy * 64 + nd)) * 128))[c8];
        *(int4*)&Ws[nd][c8 * 8] = v;
    }
    __syncthreads();

    const int lane = t & 63, wave = t >> 6;
    const int wm = (wave & 1) * 32, wn = (wave >> 1) * 32;
    const int ml = wm + (lane & 31);
    const int nl = wn + (lane & 31);
    const int koff = (lane >> 5) * 8;

    f32x16 acc;
#pragma unroll
    for (int r = 0; r < 16; r++) acc[r] = 0.f;
#pragma unroll
    for (int kk = 0; kk < 8; kk++) {
        bf16x8 a = *(const bf16x8*)&Xs[ml][kk * 16 + koff];
        bf16x8 b = *(const bf16x8*)&Ws[nl][kk * 16 + koff];
        acc = __builtin_amdgcn_mfma_f32_32x32x16_bf16(a, b, acc, 0, 0, 0);
    }

    const int col = gy * 64 + wn + (lane & 31);
    if (col < HALF) {
#pragma unroll
        for (int r = 0; r < 16; r++) {
            int row = (r & 3) + 8 * (r >> 2) + 4 * (lane >> 5);
            int node = node0 + wm + row;
            if (node < n) ybuf[(size_t)node * HALF + col] = bf16_rne(acc[r]);
        }
    } else {
        const float bj = bias[col - HALF];
#pragma unroll
        for (int r = 0; r < 16; r++) {
            int row = (r & 3) + 8 * (r >> 2) + 4 * (lane >> 5);
            int node = node0 + wm + row;
            if (node < n) rbuf[(size_t)node * HALF + (col - HALF)] = bf16_rne(acc[r] + bj);
        }
    }
}

// ---------------- place: per-bucket LDS counting sort -> rowoff + csr segment ----------------
__global__ __launch_bounds__(256) void place_kernel(
        const int* __restrict__ rec, const int* __restrict__ bcur,
        int* __restrict__ rowoff, unsigned short* __restrict__ csr, int n) {
    __shared__ int bscan[256];
    __shared__ int cnt[256];
    __shared__ int cur[256];
    __shared__ unsigned short sorted[CAP];
    const int cb = blockIdx.x, t = threadIdx.x;

    bscan[t] = (t < NB) ? bcur[t] : 0;
    __syncthreads();
    for (int ofs = 1; ofs < 256; ofs <<= 1) {
        int v = bscan[t];
        int a = (t >= ofs) ? bscan[t - ofs] : 0;
        __syncthreads();
        bscan[t] = v + a;
        __syncthreads();
    }
    const int base = (cb == 0) ? 0 : bscan[cb - 1];

    int m = bcur[cb]; if (m > CAP) m = CAP;
    const int* r = rec + (size_t)cb * CAP;

    cnt[t] = 0;
    __syncthreads();
    for (int i = t; i < m; i += 256) atomicAdd(&cnt[r[i] >> 16], 1);
    __syncthreads();
    int orig = cnt[t];
    for (int ofs = 1; ofs < 256; ofs <<= 1) {
        int v = cnt[t];
        int a = (t >= ofs) ? cnt[t - ofs] : 0;
        __syncthreads();
        cnt[t] = v + a;
        __syncthreads();
    }
    int excl = cnt[t] - orig;
    int node = cb * 256 + t;
    if (node < n) rowoff[node] = base + excl;
    if (node == n - 1) rowoff[n] = base + cnt[t];
    cur[t] = excl;
    __syncthreads();
    for (int i = t; i < m; i += 256) {
        int rr = r[i];
        int pos = atomicAdd(&cur[rr >> 16], 1);
        sorted[pos] = (unsigned short)(rr & 0xffff);
    }
    __syncthreads();
    for (int i = t; i < m; i += 256) csr[base + i] = sorted[i];
}

// ---------------- gather_l2: layer-1 gather+norm then layer-2 transform (MFMA) ----------------
// Block: 256 threads, exactly 16 nodes (NN = 3125*16). Phase 1: 16-lane group per node
// gathers y1 rows, means, adds r1, L2-norms -> Hs (bf16, LDS). Phase 2: 16x128 @ wt2
// via mfma_f32_16x16x32_bf16 -> y2 (cols<64, bf16), r2 (cols>=64, +b2, bf16).
__global__ __launch_bounds__(256) void gather_l2_kernel(
        const unsigned short* __restrict__ y, const unsigned short* __restrict__ rrb,
        const int* __restrict__ rowoff, const unsigned short* __restrict__ csr,
        const unsigned short* __restrict__ wt2, const float* __restrict__ b2,
        unsigned short* __restrict__ y2, unsigned short* __restrict__ r2, int n) {
    __shared__ unsigned short Hs[16][136];
    __shared__ unsigned short Ws[128][136];
    const int t = threadIdx.x;

    // stage wt2 (128 rows x 128 bf16)
    for (int e = t; e < 128 * 16; e += 256) {
        int nd = e >> 4, c8 = e & 15;
        int4 v = ((const int4*)(wt2 + (size_t)nd * 128))[c8];
        *(int4*)&Ws[nd][c8 * 8] = v;
    }

    // ---- phase 1: gather ----
    const int gi = t >> 4;     // group 0..15 -> node
    const int q  = t & 15;     // col chunk: cols q*8..q*8+7
    const int node = blockIdx.x * 16 + gi;   // always < n (n = 3125*16)

    const int off = rowoff[node];
    const int end = rowoff[node + 1];
    const int deg = end - off;

    float acc[8];
#pragma unroll
    for (int j = 0; j < 8; j++) acc[j] = 0.f;

    for (int k0 = 0; k0 < deg; k0 += 8) {
        int idx[8];
#pragma unroll
        for (int j = 0; j < 8; j++) {
            int kk = off + k0 + j;
            idx[j] = (kk < end) ? (int)csr[kk] : n;   // n = zero row
        }
        uint4 v[8];
#pragma unroll
        for (int j = 0; j < 8; j++)
            v[j] = *(const uint4*)(y + (size_t)idx[j] * 128 + q * 8);
#pragma unroll
        for (int j = 0; j < 8; j++) {
            const unsigned* u = (const unsigned*)&v[j];
#pragma unroll
            for (int i = 0; i < 4; i++) {
                acc[2 * i]     += bf16_lo(u[i]);
                acc[2 * i + 1] += bf16_hi(u[i]);
            }
        }
    }
    const float im = 1.0f / fmaxf((float)deg, 1.0f);
    uint4 rv = *(const uint4*)(rrb + (size_t)node * 128 + q * 8);
    const unsigned* ru = (const unsigned*)&rv;
    float v[8];
    float ss = 0.f;
#pragma unroll
    for (int i = 0; i < 4; i++) {
        v[2 * i]     = acc[2 * i] * im     + bf16_lo(ru[i]);
        v[2 * i + 1] = acc[2 * i + 1] * im + bf16_hi(ru[i]);
    }
#pragma unroll
    for (int j = 0; j < 8; j++) ss += v[j] * v[j];
#pragma unroll
    for (int m = 8; m >= 1; m >>= 1) ss += __shfl_xor(ss, m, 64);  // within 16-lane group
    const float rn = 1.0f / fmaxf(sqrtf(ss), 1e-12f);
    us4 h0, h1v;
    h0.x = bf16_rne(v[0] * rn); h0.y = bf16_rne(v[1] * rn);
    h0.z = bf16_rne(v[2] * rn); h0.w = bf16_rne(v[3] * rn);
    h1v.x = bf16_rne(v[4] * rn); h1v.y = bf16_rne(v[5] * rn);
    h1v.z = bf16_rne(v[6] * rn); h1v.w = bf16_rne(v[7] * rn);
    *(us4*)&Hs[gi][q * 8] = h0;
    *(us4*)&Hs[gi][q * 8 + 4] = h1v;
    __syncthreads();

    // ---- phase 2: 16x128 @ [W2l|W2r] ----
    const int lane = t & 63, wave = t >> 6;
    const int m16 = lane & 15;      // A row / B row(out col within tile)
    const int quad = lane >> 4;     // k sub-offset
#pragma unroll
    for (int tile = 0; tile < 2; tile++) {
        const int c0 = (wave * 2 + tile) * 16;   // out col tile base
        f32x4 c;
        c[0] = 0.f; c[1] = 0.f; c[2] = 0.f; c[3] = 0.f;
#pragma unroll
        for (int kk = 0; kk < 4; kk++) {
            bf16x8 a = *(const bf16x8*)&Hs[m16][kk * 32 + quad * 8];
            bf16x8 b = *(const bf16x8*)&Ws[c0 + m16][kk * 32 + quad * 8];
            c = __builtin_amdgcn_mfma_f32_16x16x32_bf16(a, b, c, 0, 0, 0);
        }
        const int col = c0 + m16;
#pragma unroll
        for (int r = 0; r < 4; r++) {
            int row = quad * 4 + r;
            int nd = blockIdx.x * 16 + row;
            if (col < 64) y2[(size_t)nd * 64 + col] = bf16_rne(c[r]);
            else          r2[(size_t)nd * 64 + (col - 64)] = bf16_rne(c[r] + b2[col - 64]);
        }
    }
}

// ---------------- gather + mean + add-root + L2norm, D=64, fp32 out ----------------
__global__ __launch_bounds__(256) void gather64_kernel(
        const unsigned short* __restrict__ y, const unsigned short* __restrict__ rrb,
        const int* __restrict__ rowoff, const unsigned short* __restrict__ csr,
        float* __restrict__ out, int n) {
    const int gi = threadIdx.x >> 3;     // group 0..31
    const int q  = threadIdx.x & 7;      // col chunk: cols q*8..q*8+7
    const int node = blockIdx.x * 32 + gi;
    if (node >= n) return;

    const int off = rowoff[node];
    const int end = rowoff[node + 1];
    const int deg = end - off;

    float acc[8];
#pragma unroll
    for (int j = 0; j < 8; j++) acc[j] = 0.f;

    for (int k0 = 0; k0 < deg; k0 += 8) {
        int idx[8];
#pragma unroll
        for (int j = 0; j < 8; j++) {
            int kk = off + k0 + j;
            idx[j] = (kk < end) ? (int)csr[kk] : n;
        }
        uint4 v[8];
#pragma unroll
        for (int j = 0; j < 8; j++)
            v[j] = *(const uint4*)(y + (size_t)idx[j] * 64 + q * 8);
#pragma unroll
        for (int j = 0; j < 8; j++) {
            const unsigned* u = (const unsigned*)&v[j];
#pragma unroll
            for (int i = 0; i < 4; i++) {
                acc[2 * i]     += bf16_lo(u[i]);
                acc[2 * i + 1] += bf16_hi(u[i]);
            }
        }
    }
    const float im = 1.0f / fmaxf((float)deg, 1.0f);
    uint4 rv = *(const uint4*)(rrb + (size_t)node * 64 + q * 8);
    const unsigned* ru = (const unsigned*)&rv;
    float v[8];
    float ss = 0.f;
#pragma unroll
    for (int i = 0; i < 4; i++) {
        v[2 * i]     = acc[2 * i] * im     + bf16_lo(ru[i]);
        v[2 * i + 1] = acc[2 * i + 1] * im + bf16_hi(ru[i]);
    }
#pragma unroll
    for (int j = 0; j < 8; j++) ss += v[j] * v[j];
#pragma unroll
    for (int m = 4; m >= 1; m >>= 1) ss += __shfl_xor(ss, m, 64);  // within 8-lane group
    const float rn = 1.0f / fmaxf(sqrtf(ss), 1e-12f);
    float4 o0 = make_float4(v[0] * rn, v[1] * rn, v[2] * rn, v[3] * rn);
    float4 o1 = make_float4(v[4] * rn, v[5] * rn, v[6] * rn, v[7] * rn);
    *(float4*)(out + (size_t)node * 64 + q * 8) = o0;
    *(float4*)(out + (size_t)node * 64 + q * 8 + 4) = o1;
}

extern "C" void kernel_launch(void* const* d_in, const int* in_sizes, int n_in,
                              void* d_out, int out_size, void* d_ws, size_t ws_size,
                              hipStream_t stream) {
    const float* x   = (const float*)d_in[0];
    const int*   ei  = (const int*)d_in[1];   // [2, E] int32
    const float* w1l = (const float*)d_in[2];
    const float* b1  = (const float*)d_in[3];
    const float* w1r = (const float*)d_in[4];
    const float* w2l = (const float*)d_in[5];
    const float* b2  = (const float*)d_in[6];
    const float* w2r = (const float*)d_in[7];
    float* out = (float*)d_out;

    const int* src = ei;
    const int* dst = ei + EE;

    char* ws = (char*)d_ws;
    auto align = [](size_t v) { return (v + 255) & ~(size_t)255; };
    int*   rowoff = (int*)ws;                 size_t o = align((size_t)(NN + 1) * 4);
    int*   bcur   = (int*)(ws + o);           o += align((size_t)NB * 4);
    int*   rec    = (int*)(ws + o);           o += align((size_t)NB * CAP * 4);     // 4.8 MB
    unsigned short* csr = (unsigned short*)(ws + o); o += align((size_t)EE * 2);    // 1.6 MB
    unsigned short* wt1 = (unsigned short*)(ws + o); o += align((size_t)256 * 128 * 2);
    unsigned short* wt2 = (unsigned short*)(ws + o); o += align((size_t)128 * 128 * 2);
    unsigned short* y1  = (unsigned short*)(ws + o); o += align((size_t)(NN + 1) * 128 * 2);
    unsigned short* r1  = (unsigned short*)(ws + o); o += align((size_t)NN * 128 * 2);
    unsigned short* y2  = (unsigned short*)(ws + o); o += align((size_t)(NN + 1) * 64 * 2);
    unsigned short* r2  = (unsigned short*)(ws + o); o += align((size_t)NN * 64 * 2);

    // ---- prep (weights + pad rows + bcur=0) ----
    prep_all_kernel<<<194, 256, 0, stream>>>(w1l, w1r, w2l, w2r, wt1, wt2,
                                             y1 + (size_t)NN * 128, y2 + (size_t)NN * 64, bcur);
    // ---- fused transform1 + bin ----
    fused_t1_bin_kernel<<<TB1 + NBIN, 256, 0, stream>>>(
        x, wt1, b1, y1, r1, NN, src, dst, bcur, rec, EE);
    // ---- place: CSR finalize ----
    place_kernel<<<NB, 256, 0, stream>>>(rec, bcur, rowoff, csr, NN);
    // ---- layer-1 gather + layer-2 transform fused ----
    gather_l2_kernel<<<NN / 16, 256, 0, stream>>>(y1, r1, rowoff, csr, wt2, b2, y2, r2, NN);
    // ---- layer-2 gather -> out fp32 ----
    gather64_kernel<<<(NN + 31) / 32, 256, 0, stream>>>(y2, r2, rowoff, csr, out, NN);
}